// Round 2
// baseline (774.031 us; speedup 1.0000x reference)
//
#include <hip/hip_runtime.h>
#include <hip/hip_bf16.h>
#include <stdint.h>

typedef __bf16 bf16_t;
typedef __bf16 bf16x8 __attribute__((ext_vector_type(8)));
typedef float f32x4 __attribute__((ext_vector_type(4)));

#define NROW 6000           // rows of each graph
#define HID 256
#define NHEAD 4
#define HD 64
#define ATT_SCALE 0.125f    // HEAD_DIM^-0.5 = 1/8
#define MTOT 12000          // both graphs concatenated
#define CAP_NNZ 1000000     // nnz ~ 360K expected; safety cap

// ---------------- dtype detection -------------------------------------------
// alignment_matrix holds exactly {0.0, 1.0}. If stored f32, every EVEN
// halfword is 0x0000 (low mantissa of 0.0/1.0 is zero). If stored bf16,
// ~1% of even halfwords equal 0x3F80. flag=1 -> bf16, flag=0 -> f32.
__global__ __launch_bounds__(256)
void detect_kernel(const unsigned short* __restrict__ a, int* __restrict__ flag)
{
    int t = threadIdx.x;
    int found = 0;
    for (int k = t; k < 102400; k += 256)
        if (a[2 * k] != 0) found = 1;
    if (found) atomicOr(flag, 1);
}

// ---------------- canonicalize any dense tensor to bf16 ---------------------
__global__ __launch_bounds__(256)
void canon_kernel(const void* __restrict__ src, bf16_t* __restrict__ dst, int n,
                  const int* __restrict__ flag)
{
    __shared__ int fb;
    if (threadIdx.x == 0) fb = *flag;
    __syncthreads();
    int i = blockIdx.x * 256 + threadIdx.x;
    if (i >= n) return;
    dst[i] = fb ? ((const bf16_t*)src)[i] : (bf16_t)(((const float*)src)[i]);
}

// ---------------- QKV projection: [12000,256] @ {Wq,Wk,Wv}^T + bias ----------
__global__ __launch_bounds__(256)
void proj_qkv_kernel(const bf16_t* __restrict__ e12,   // canon [12000,256]
                     const bf16_t* __restrict__ wq, const bf16_t* __restrict__ wk,
                     const bf16_t* __restrict__ wv,
                     const bf16_t* __restrict__ bq, const bf16_t* __restrict__ bk,
                     const bf16_t* __restrict__ bv,
                     float* __restrict__ Q, float* __restrict__ Kf, bf16_t* __restrict__ V)
{
    int m0   = blockIdx.x * 64;
    int n0   = blockIdx.y * 64;      // global output col in [0,768)
    int wave = threadIdx.x >> 6;
    int lane = threadIdx.x & 63;
    int r16  = lane & 15;
    int quad = lane >> 4;

    int sel = n0 >> 8;               // 0=Q, 1=K, 2=V
    int jb  = n0 & 255;
    const bf16_t* W; const bf16_t* bias;
    if (sel == 0)      { W = wq; bias = bq; }
    else if (sel == 1) { W = wk; bias = bk; }
    else               { W = wv; bias = bv; }

    int arow = m0 + wave * 16 + r16;
    int rr   = arow < MTOT ? arow : MTOT - 1;
    const bf16_t* asrc = e12 + (size_t)rr * HID;

    f32x4 acc0 = {0,0,0,0}, acc1 = {0,0,0,0}, acc2 = {0,0,0,0}, acc3 = {0,0,0,0};
#pragma unroll
    for (int kk = 0; kk < HID; kk += 32) {
        bf16x8 a = *(const bf16x8*)(asrc + kk + quad * 8);
        const bf16_t* b0 = W + (size_t)(jb + r16) * HID + kk + quad * 8;
        bf16x8 f0 = *(const bf16x8*)(b0);
        bf16x8 f1 = *(const bf16x8*)(b0 + 16 * HID);
        bf16x8 f2 = *(const bf16x8*)(b0 + 32 * HID);
        bf16x8 f3 = *(const bf16x8*)(b0 + 48 * HID);
        acc0 = __builtin_amdgcn_mfma_f32_16x16x32_bf16(a, f0, acc0, 0, 0, 0);
        acc1 = __builtin_amdgcn_mfma_f32_16x16x32_bf16(a, f1, acc1, 0, 0, 0);
        acc2 = __builtin_amdgcn_mfma_f32_16x16x32_bf16(a, f2, acc2, 0, 0, 0);
        acc3 = __builtin_amdgcn_mfma_f32_16x16x32_bf16(a, f3, acc3, 0, 0, 0);
    }
    f32x4 accs[4] = {acc0, acc1, acc2, acc3};
    int rbase = m0 + wave * 16 + quad * 4;
#pragma unroll
    for (int nt = 0; nt < 4; ++nt) {
        int j = jb + nt * 16 + r16;
        float bb = (float)bias[j];
#pragma unroll
        for (int rg = 0; rg < 4; ++rg) {
            int r = rbase + rg;
            if (r < MTOT) {
                float v = accs[nt][rg] + bb;
                if (sel == 0)      Q [(size_t)r * HID + j] = v;
                else if (sel == 1) Kf[(size_t)r * HID + j] = v;
                else               V [(size_t)r * HID + j] = (bf16_t)v;
            }
        }
    }
}

// ---------------- Kbar = mean over 4 heads of K ------------------------------
__global__ __launch_bounds__(256)
void kbar_kernel(const float* __restrict__ Kf, float* __restrict__ Kbar)
{
    int id = blockIdx.x * 256 + threadIdx.x;   // [0, 12000*64)
    if (id >= MTOT * HD) return;
    int m = id >> 6, d = id & 63;
    const float* kr = Kf + (size_t)m * HID + d;
    Kbar[id] = 0.25f * (kr[0] + kr[64] + kr[128] + kr[192]);
}

// ---------------- Vsum[g][j] = sum_m V[g*6000+m][j] --------------------------
__global__ __launch_bounds__(256)
void vsum_kernel(const bf16_t* __restrict__ V, float* __restrict__ Vsum)
{
    int g = blockIdx.x;          // graph 0/1
    int b = blockIdx.y;          // 24 row segments of 250
    int j = threadIdx.x;
    const bf16_t* base = V + ((size_t)(g * NROW + b * 250)) * HID + j;
    float s = 0.f;
    for (int m = 0; m < 250; ++m) s += (float)base[(size_t)m * HID];
    atomicAdd(Vsum + g * HID + j, s);
}

// ---------------- sparse align extraction (dual dtype) -----------------------
__global__ __launch_bounds__(256)
void count_nz_kernel(const void* __restrict__ av,
                     int* __restrict__ rc, int* __restrict__ cc,
                     const int* __restrict__ flag)
{
    __shared__ int fb;
    if (threadIdx.x == 0) fb = *flag;
    __syncthreads();
    int ch = blockIdx.x * 256 + threadIdx.x;        // chunk of 8 elements
    const int NCH = (NROW * NROW) / 8;              // 4,500,000
    if (ch >= NCH) return;
    unsigned int nzmask = 0;                        // bit p = element ch*8+p nonzero
    if (fb) {
        uint4 u = *(const uint4*)((const unsigned short*)av + (size_t)ch * 8);
        unsigned int w[4] = {u.x, u.y, u.z, u.w};
#pragma unroll
        for (int p = 0; p < 4; ++p) {
            if (w[p] & 0xFFFFu)  nzmask |= 1u << (2 * p);
            if (w[p] >> 16)      nzmask |= 1u << (2 * p + 1);
        }
    } else {
        const unsigned int* aw = (const unsigned int*)av + (size_t)ch * 8;
        uint4 u0 = *(const uint4*)(aw);
        uint4 u1 = *(const uint4*)(aw + 4);
        unsigned int w[8] = {u0.x, u0.y, u0.z, u0.w, u1.x, u1.y, u1.z, u1.w};
#pragma unroll
        for (int p = 0; p < 8; ++p)
            if (w[p]) nzmask |= 1u << p;
    }
    int base = ch * 8;
#pragma unroll
    for (int p = 0; p < 8; ++p) {
        if (nzmask & (1u << p)) {
            int e = base + p; int n = e / NROW; int m = e - n * NROW;
            atomicAdd(rc + n, 1); atomicAdd(cc + m, 1);
        }
    }
}

__global__ __launch_bounds__(256)
void prefix_kernel(const int* __restrict__ rc, const int* __restrict__ cc,
                   int* __restrict__ rptr, int* __restrict__ cptr,
                   int* __restrict__ rcur, int* __restrict__ ccur)
{
    const int* cnt = blockIdx.x ? cc : rc;
    int* ptr = blockIdx.x ? cptr : rptr;
    int* cur = blockIdx.x ? ccur : rcur;
    __shared__ int part[256];
    int t = threadIdx.x;
    const int SEG = 24;                     // 256*24 >= 6000
    int s0 = t * SEG;
    int sum = 0;
    for (int k = 0; k < SEG; ++k) { int i = s0 + k; if (i < NROW) sum += cnt[i]; }
    part[t] = sum;
    __syncthreads();
    if (t == 0) {
        int run = 0;
        for (int k = 0; k < 256; ++k) { int tmp = part[k]; part[k] = run; run += tmp; }
        ptr[NROW] = run;
    }
    __syncthreads();
    int run = part[t];
    for (int k = 0; k < SEG; ++k) {
        int i = s0 + k;
        if (i < NROW) { ptr[i] = run; cur[i] = run; run += cnt[i]; }
    }
}

__global__ __launch_bounds__(256)
void fill_nz_kernel(const void* __restrict__ av,
                    int* __restrict__ rcur, int* __restrict__ ccur,
                    int* __restrict__ csr_cols, int* __restrict__ csc_rows,
                    const int* __restrict__ flag)
{
    __shared__ int fb;
    if (threadIdx.x == 0) fb = *flag;
    __syncthreads();
    int ch = blockIdx.x * 256 + threadIdx.x;
    const int NCH = (NROW * NROW) / 8;
    if (ch >= NCH) return;
    unsigned int nzmask = 0;
    if (fb) {
        uint4 u = *(const uint4*)((const unsigned short*)av + (size_t)ch * 8);
        unsigned int w[4] = {u.x, u.y, u.z, u.w};
#pragma unroll
        for (int p = 0; p < 4; ++p) {
            if (w[p] & 0xFFFFu)  nzmask |= 1u << (2 * p);
            if (w[p] >> 16)      nzmask |= 1u << (2 * p + 1);
        }
    } else {
        const unsigned int* aw = (const unsigned int*)av + (size_t)ch * 8;
        uint4 u0 = *(const uint4*)(aw);
        uint4 u1 = *(const uint4*)(aw + 4);
        unsigned int w[8] = {u0.x, u0.y, u0.z, u0.w, u1.x, u1.y, u1.z, u1.w};
#pragma unroll
        for (int p = 0; p < 8; ++p)
            if (w[p]) nzmask |= 1u << p;
    }
    int base = ch * 8;
#pragma unroll
    for (int p = 0; p < 8; ++p) {
        if (nzmask & (1u << p)) {
            int e = base + p;
            int n = e / NROW; int m = e - n * NROW;
            int pr = atomicAdd(rcur + n, 1);
            if (pr < CAP_NNZ) csr_cols[pr] = m;
            int pc = atomicAdd(ccur + m, 1);
            if (pc < CAP_NNZ) csc_rows[pc] = n;
        }
    }
}

// ---------------- sparse-corrected attention ---------------------------------
// One block per query row. Exact softmax over 6000 kv entries using the
// "all masked-out entries share weight exp(-M)/Z" identity.
__global__ __launch_bounds__(256)
void attn_kernel(const float* __restrict__ Qbase,   // query rows (n*256)
                 const float* __restrict__ Kbar,    // kv-side head-mean K (m*64)
                 const bf16_t* __restrict__ V,      // kv-side V (m*256)
                 const float* __restrict__ Vsum,    // [256] per-head V column sums
                 const int* __restrict__ ptr, const int* __restrict__ cnt_arr,
                 const int* __restrict__ lst,
                 bf16_t* __restrict__ att)          // out rows (n*256)
{
    __shared__ float qs[HID];
    __shared__ int   ml[256];
    __shared__ float sc[256 * 5];   // [j][head], stride 5 to dodge bank conflicts
    __shared__ float w0s[NHEAD];

    int n = blockIdx.x;
    int t = threadIdx.x;
    int head = t >> 6, l = t & 63;

    int p0  = ptr[n];
    int cnt = cnt_arr[n];
    if (cnt > 256) cnt = 256;       // Binom(6000,0.01): P(>256) ~ 0

    qs[t] = Qbase[(size_t)n * HID + t];
    for (int j = t; j < cnt; j += 256) ml[j] = lst[p0 + j];
    __syncthreads();

    // phase 1: scores s[j][head] = SCALE * dot64(q_head, Kbar[m_j])
    for (int jb2 = 0; jb2 < cnt; jb2 += 64) {
        int j = jb2 + l;
        if (j < cnt) {
            int m = ml[j];
            const float* kb = Kbar + (size_t)m * HD;
            const float* qh = qs + head * HD;
            float dot = 0.f;
#pragma unroll
            for (int d = 0; d < HD; d += 4) {
                f32x4 k4 = *(const f32x4*)(kb + d);
                dot += qh[d] * k4[0] + qh[d+1] * k4[1] + qh[d+2] * k4[2] + qh[d+3] * k4[3];
            }
            sc[j * 5 + head] = dot * ATT_SCALE;
        }
    }
    __syncthreads();

    // phase 2: per-head exact softmax stats; wave `head` owns head `head`
    {
        float M = 0.0f;             // zero-score baseline always present
        for (int j = l; j < cnt; j += 64) M = fmaxf(M, sc[j * 5 + head]);
        for (int off = 32; off; off >>= 1) M = fmaxf(M, __shfl_xor(M, off));
        float e0 = __expf(-M);
        float e[4]; int k = 0;
        float S = 0.f;
        for (int j = l; j < cnt; j += 64, ++k) { e[k] = __expf(sc[j * 5 + head] - M); S += e[k]; }
        for (int off = 32; off; off >>= 1) S += __shfl_xor(S, off);
        float Z = S + (float)(NROW - cnt) * e0;
        float invZ = 1.0f / Z;
        k = 0;
        for (int j = l; j < cnt; j += 64, ++k) sc[j * 5 + head] = (e[k] - e0) * invZ;
        if (l == 0) w0s[head] = e0 * invZ;
    }
    __syncthreads();

    // phase 3: out[head][d] = w0*Vsum + sum_j coef_j * V[m_j][head*64+d]
    float acc = w0s[head] * Vsum[head * HD + l];
    for (int j = 0; j < cnt; ++j) {
        float c = sc[j * 5 + head];
        int m = ml[j];
        acc += c * (float)V[(size_t)m * HID + head * HD + l];
    }
    att[(size_t)n * HID + head * HD + l] = (bf16_t)acc;
}

// ---------------- final projection + residual (dual dtype I/O) ---------------
__global__ __launch_bounds__(256)
void proj_out_kernel(const bf16_t* __restrict__ att, const bf16_t* __restrict__ wo,
                     const bf16_t* __restrict__ bo,
                     const void* __restrict__ e1v, const void* __restrict__ e2v,
                     void* __restrict__ outv, const int* __restrict__ flag)
{
    __shared__ int fb;
    if (threadIdx.x == 0) fb = *flag;
    __syncthreads();

    int m0   = blockIdx.x * 64;
    int n0   = blockIdx.y * 64;      // in [0,256)
    int wave = threadIdx.x >> 6;
    int lane = threadIdx.x & 63;
    int r16  = lane & 15;
    int quad = lane >> 4;

    int arow = m0 + wave * 16 + r16;
    int rr   = arow < MTOT ? arow : MTOT - 1;
    const bf16_t* asrc = att + (size_t)rr * HID;

    f32x4 acc0 = {0,0,0,0}, acc1 = {0,0,0,0}, acc2 = {0,0,0,0}, acc3 = {0,0,0,0};
#pragma unroll
    for (int kk = 0; kk < HID; kk += 32) {
        bf16x8 a = *(const bf16x8*)(asrc + kk + quad * 8);
        const bf16_t* b0 = wo + (size_t)(n0 + r16) * HID + kk + quad * 8;
        bf16x8 f0 = *(const bf16x8*)(b0);
        bf16x8 f1 = *(const bf16x8*)(b0 + 16 * HID);
        bf16x8 f2 = *(const bf16x8*)(b0 + 32 * HID);
        bf16x8 f3 = *(const bf16x8*)(b0 + 48 * HID);
        acc0 = __builtin_amdgcn_mfma_f32_16x16x32_bf16(a, f0, acc0, 0, 0, 0);
        acc1 = __builtin_amdgcn_mfma_f32_16x16x32_bf16(a, f1, acc1, 0, 0, 0);
        acc2 = __builtin_amdgcn_mfma_f32_16x16x32_bf16(a, f2, acc2, 0, 0, 0);
        acc3 = __builtin_amdgcn_mfma_f32_16x16x32_bf16(a, f3, acc3, 0, 0, 0);
    }
    f32x4 accs[4] = {acc0, acc1, acc2, acc3};
    int rbase = m0 + wave * 16 + quad * 4;
#pragma unroll
    for (int nt = 0; nt < 4; ++nt) {
        int j = n0 + nt * 16 + r16;
        float bb = (float)bo[j];
#pragma unroll
        for (int rg = 0; rg < 4; ++rg) {
            int r = rbase + rg;
            if (r < MTOT) {
                const void* eb = (r < NROW) ? e1v : e2v;
                size_t eidx = (size_t)((r < NROW) ? r : r - NROW) * HID + j;
                float ev = fb ? (float)((const bf16_t*)eb)[eidx]
                              : ((const float*)eb)[eidx];
                float v = accs[nt][rg] + bb + ev;
                size_t oidx = (size_t)r * HID + j;   // concat layout: row r -> r*256
                if (fb) ((bf16_t*)outv)[oidx] = (bf16_t)v;
                else    ((float*)outv)[oidx]  = v;
            }
        }
    }
}

// ---------------- host launcher ----------------------------------------------
extern "C" void kernel_launch(void* const* d_in, const int* in_sizes, int n_in,
                              void* d_out, int out_size, void* d_ws, size_t ws_size,
                              hipStream_t stream)
{
    const void* e1v = d_in[0];
    const void* e2v = d_in[1];
    const void* alv = d_in[2];
    const void* wqv = d_in[3];
    const void* bqv = d_in[4];
    const void* wkv = d_in[5];
    const void* bkv = d_in[6];
    const void* wvv = d_in[7];
    const void* bvv = d_in[8];
    const void* wov = d_in[9];
    const void* bov = d_in[10];

    size_t off = 0;
    char* base = (char*)d_ws;
    auto alloc = [&](size_t bytes) -> void* {
        void* p = base + off;
        off += (bytes + 255) & ~(size_t)255;
        return p;
    };
    float*  Q        = (float*) alloc((size_t)MTOT * HID * 4);
    float*  Kf       = (float*) alloc((size_t)MTOT * HID * 4);
    bf16_t* V        = (bf16_t*)alloc((size_t)MTOT * HID * 2);
    float*  Kbar     = (float*) alloc((size_t)MTOT * HD * 4);
    bf16_t* att      = (bf16_t*)alloc((size_t)MTOT * HID * 2);
    bf16_t* cE       = (bf16_t*)alloc((size_t)MTOT * HID * 2);   // canon e1|e2
    bf16_t* cWq      = (bf16_t*)alloc((size_t)HID * HID * 2);
    bf16_t* cWk      = (bf16_t*)alloc((size_t)HID * HID * 2);
    bf16_t* cWv      = (bf16_t*)alloc((size_t)HID * HID * 2);
    bf16_t* cWo      = (bf16_t*)alloc((size_t)HID * HID * 2);
    bf16_t* cB       = (bf16_t*)alloc((size_t)4 * HID * 2);      // bq|bk|bv|bo
    int*    flag     = (int*)   alloc(256);                      // dtype flag
    int*    row_cnt  = (int*)   alloc(NROW * 4);
    int*    col_cnt  = (int*)   alloc(NROW * 4);
    float*  Vsum     = (float*) alloc(2 * HID * 4);
    int*    row_ptr  = (int*)   alloc((NROW + 1) * 4);
    int*    col_ptr  = (int*)   alloc((NROW + 1) * 4);
    int*    cur_row  = (int*)   alloc(NROW * 4);
    int*    cur_col  = (int*)   alloc(NROW * 4);
    int*    csr_cols = (int*)   alloc((size_t)CAP_NNZ * 4);
    int*    csc_rows = (int*)   alloc((size_t)CAP_NNZ * 4);

    // zero flag + counters + Vsum (contiguous region)
    size_t zero_bytes = (size_t)((char*)Vsum - (char*)flag) + 2 * HID * 4;
    hipMemsetAsync(flag, 0, zero_bytes, stream);

    // dtype detection from alignment matrix bit patterns
    detect_kernel<<<1, 256, 0, stream>>>((const unsigned short*)alv, flag);

    // canonicalize inputs to bf16
    const int NE = NROW * HID;                    // 1,536,000
    canon_kernel<<<(NE + 255) / 256, 256, 0, stream>>>(e1v, cE, NE, flag);
    canon_kernel<<<(NE + 255) / 256, 256, 0, stream>>>(e2v, cE + (size_t)NROW * HID, NE, flag);
    canon_kernel<<<256, 256, 0, stream>>>(wqv, cWq, HID * HID, flag);
    canon_kernel<<<256, 256, 0, stream>>>(wkv, cWk, HID * HID, flag);
    canon_kernel<<<256, 256, 0, stream>>>(wvv, cWv, HID * HID, flag);
    canon_kernel<<<256, 256, 0, stream>>>(wov, cWo, HID * HID, flag);
    canon_kernel<<<1, 256, 0, stream>>>(bqv, cB, HID, flag);
    canon_kernel<<<1, 256, 0, stream>>>(bkv, cB + HID, HID, flag);
    canon_kernel<<<1, 256, 0, stream>>>(bvv, cB + 2 * HID, HID, flag);
    canon_kernel<<<1, 256, 0, stream>>>(bov, cB + 3 * HID, HID, flag);

    // projections
    proj_qkv_kernel<<<dim3(188, 12), 256, 0, stream>>>(
        cE, cWq, cWk, cWv, cB, cB + HID, cB + 2 * HID, Q, Kf, V);
    kbar_kernel<<<(MTOT * HD + 255) / 256, 256, 0, stream>>>(Kf, Kbar);
    vsum_kernel<<<dim3(2, 24), 256, 0, stream>>>(V, Vsum);

    // sparse structure of align
    const int NCH = (NROW * NROW) / 8;
    int nblk = (NCH + 255) / 256;
    count_nz_kernel<<<nblk, 256, 0, stream>>>(alv, row_cnt, col_cnt, flag);
    prefix_kernel<<<2, 256, 0, stream>>>(row_cnt, col_cnt, row_ptr, col_ptr, cur_row, cur_col);
    fill_nz_kernel<<<nblk, 256, 0, stream>>>(alv, cur_row, cur_col, csr_cols, csc_rows, flag);

    // direction 1: kg1 queries, kg2 kv, CSR rows
    attn_kernel<<<NROW, 256, 0, stream>>>(
        Q, Kbar + (size_t)NROW * HD, V + (size_t)NROW * HID, Vsum + HID,
        row_ptr, row_cnt, csr_cols, att);
    // direction 2: kg2 queries, kg1 kv, CSC cols
    attn_kernel<<<NROW, 256, 0, stream>>>(
        Q + (size_t)NROW * HID, Kbar, V, Vsum,
        col_ptr, col_cnt, csc_rows, att + (size_t)NROW * HID);

    // final projection + residual, both graphs
    proj_out_kernel<<<dim3(188, 4), 256, 0, stream>>>(att, cWo, cB + 3 * HID, e1v, e2v, d_out, flag);
}

// Round 3
// 559.686 us; speedup vs baseline: 1.3830x; 1.3830x over previous
//
#include <hip/hip_runtime.h>
#include <hip/hip_bf16.h>
#include <stdint.h>

typedef __bf16 bf16_t;
typedef __bf16 bf16x8 __attribute__((ext_vector_type(8)));
typedef float f32x4 __attribute__((ext_vector_type(4)));

#define NROW 6000           // rows of each graph
#define HID 256
#define NHEAD 4
#define HD 64
#define ATT_SCALE 0.125f    // HEAD_DIM^-0.5 = 1/8
#define MTOT 12000          // both graphs concatenated
#define CAP 128             // ELL capacity; Binom(6000,0.01) mean 60, sd 7.7 -> 8.8 sigma
#define NCHUNK 4500000      // 6000*6000/8 ; 750 chunks per row exactly

// ---------------- dtype detection -------------------------------------------
// alignment_matrix holds exactly {0.0, 1.0}. If stored f32, every EVEN
// halfword is 0x0000. If bf16, ~1% of even halfwords are 0x3F80.
__global__ __launch_bounds__(256)
void detect_kernel(const unsigned short* __restrict__ a, int* __restrict__ flag)
{
    int t = threadIdx.x;
    int found = 0;
    for (int k = t; k < 102400; k += 256)
        if (a[2 * k] != 0) found = 1;
    if (found) atomicOr(flag, 1);
}

// ---------------- canonicalize embeddings (both graphs) ----------------------
__global__ __launch_bounds__(256)
void canon_emb_kernel(const void* __restrict__ e1, const void* __restrict__ e2,
                      bf16_t* __restrict__ dst, const int* __restrict__ flag)
{
    __shared__ int fb;
    if (threadIdx.x == 0) fb = *flag;
    __syncthreads();
    int i = blockIdx.x * 256 + threadIdx.x;
    const int NE = NROW * HID;
    if (i >= 2 * NE) return;
    const void* src = (i < NE) ? e1 : e2;
    int k = (i < NE) ? i : i - NE;
    dst[i] = fb ? ((const bf16_t*)src)[k] : (bf16_t)(((const float*)src)[k]);
}

// ---------------- canonicalize weights + biases ------------------------------
// dst layout: Wq|Wk|Wv|Wo (4*65536) then bq|bk|bv|bo (4*256)
__global__ __launch_bounds__(256)
void canon_wb_kernel(const void* __restrict__ wq, const void* __restrict__ wk,
                     const void* __restrict__ wv, const void* __restrict__ wo,
                     const void* __restrict__ bq, const void* __restrict__ bk,
                     const void* __restrict__ bv, const void* __restrict__ bo,
                     bf16_t* __restrict__ dst, const int* __restrict__ flag)
{
    __shared__ int fb;
    if (threadIdx.x == 0) fb = *flag;
    __syncthreads();
    int i = blockIdx.x * 256 + threadIdx.x;
    const int NW = 4 * HID * HID;               // 262144
    if (i >= NW + 4 * HID) return;
    const void* src; int k;
    if (i < NW) {
        int seg = i >> 16; k = i & 65535;
        src = (seg == 0) ? wq : (seg == 1) ? wk : (seg == 2) ? wv : wo;
    } else {
        int r = i - NW; int seg = r >> 8; k = r & 255;
        src = (seg == 0) ? bq : (seg == 1) ? bk : (seg == 2) ? bv : bo;
    }
    dst[i] = fb ? ((const bf16_t*)src)[k] : (bf16_t)(((const float*)src)[k]);
}

// ---------------- QKV projection: [12000,256] @ {Wq,Wk,Wv}^T + bias ----------
__global__ __launch_bounds__(256)
void proj_qkv_kernel(const bf16_t* __restrict__ e12,
                     const bf16_t* __restrict__ wq, const bf16_t* __restrict__ wk,
                     const bf16_t* __restrict__ wv,
                     const bf16_t* __restrict__ bq, const bf16_t* __restrict__ bk,
                     const bf16_t* __restrict__ bv,
                     float* __restrict__ Q, float* __restrict__ Kf, bf16_t* __restrict__ V)
{
    int m0   = blockIdx.x * 64;
    int n0   = blockIdx.y * 64;      // global output col in [0,768)
    int wave = threadIdx.x >> 6;
    int lane = threadIdx.x & 63;
    int r16  = lane & 15;
    int quad = lane >> 4;

    int sel = n0 >> 8;               // 0=Q, 1=K, 2=V
    int jb  = n0 & 255;
    const bf16_t* W; const bf16_t* bias;
    if (sel == 0)      { W = wq; bias = bq; }
    else if (sel == 1) { W = wk; bias = bk; }
    else               { W = wv; bias = bv; }

    int arow = m0 + wave * 16 + r16;
    int rr   = arow < MTOT ? arow : MTOT - 1;
    const bf16_t* asrc = e12 + (size_t)rr * HID;

    f32x4 acc0 = {0,0,0,0}, acc1 = {0,0,0,0}, acc2 = {0,0,0,0}, acc3 = {0,0,0,0};
#pragma unroll
    for (int kk = 0; kk < HID; kk += 32) {
        bf16x8 a = *(const bf16x8*)(asrc + kk + quad * 8);
        const bf16_t* b0 = W + (size_t)(jb + r16) * HID + kk + quad * 8;
        bf16x8 f0 = *(const bf16x8*)(b0);
        bf16x8 f1 = *(const bf16x8*)(b0 + 16 * HID);
        bf16x8 f2 = *(const bf16x8*)(b0 + 32 * HID);
        bf16x8 f3 = *(const bf16x8*)(b0 + 48 * HID);
        acc0 = __builtin_amdgcn_mfma_f32_16x16x32_bf16(a, f0, acc0, 0, 0, 0);
        acc1 = __builtin_amdgcn_mfma_f32_16x16x32_bf16(a, f1, acc1, 0, 0, 0);
        acc2 = __builtin_amdgcn_mfma_f32_16x16x32_bf16(a, f2, acc2, 0, 0, 0);
        acc3 = __builtin_amdgcn_mfma_f32_16x16x32_bf16(a, f3, acc3, 0, 0, 0);
    }
    f32x4 accs[4] = {acc0, acc1, acc2, acc3};
    int rbase = m0 + wave * 16 + quad * 4;
#pragma unroll
    for (int nt = 0; nt < 4; ++nt) {
        int j = jb + nt * 16 + r16;
        float bb = (float)bias[j];
#pragma unroll
        for (int rg = 0; rg < 4; ++rg) {
            int r = rbase + rg;
            if (r < MTOT) {
                float v = accs[nt][rg] + bb;
                if (sel == 0)      Q [(size_t)r * HID + j] = v;
                else if (sel == 1) Kf[(size_t)r * HID + j] = v;
                else               V [(size_t)r * HID + j] = (bf16_t)v;
            }
        }
    }
}

// ---------------- Kbar = mean over 4 heads of K ------------------------------
__global__ __launch_bounds__(256)
void kbar_kernel(const float* __restrict__ Kf, float* __restrict__ Kbar)
{
    int id = blockIdx.x * 256 + threadIdx.x;   // [0, 12000*64)
    if (id >= MTOT * HD) return;
    int m = id >> 6, d = id & 63;
    const float* kr = Kf + (size_t)m * HID + d;
    Kbar[id] = 0.25f * (kr[0] + kr[64] + kr[128] + kr[192]);
}

// ---------------- Vsum[g][j] = sum_m V[g*6000+m][j] --------------------------
__global__ __launch_bounds__(256)
void vsum_kernel(const bf16_t* __restrict__ V, float* __restrict__ Vsum)
{
    int g = blockIdx.x;          // graph 0/1
    int b = blockIdx.y;          // 24 row segments of 250
    int j = threadIdx.x;
    const bf16_t* base = V + ((size_t)(g * NROW + b * 250)) * HID + j;
    float s = 0.f;
    for (int m = 0; m < 250; ++m) s += (float)base[(size_t)m * HID];
    atomicAdd(Vsum + g * HID + j, s);
}

// ---------------- single-pass wave-aggregated ELL extraction -----------------
// Each thread owns 8 consecutive elements (one chunk); 750 chunks per row
// exactly, so a 64-lane wave straddles at most 2 rows. One atomicAdd per
// row-segment per wave (~1.1/wave), contiguous appends.
__global__ __launch_bounds__(256)
void scan_nz_kernel(const void* __restrict__ av,
                    int* __restrict__ rcur,           // [NROW] row counts (pre-zeroed)
                    int* __restrict__ csr,            // [NROW*CAP] column lists
                    const int* __restrict__ flag)
{
    __shared__ int fb;
    if (threadIdx.x == 0) fb = *flag;
    __syncthreads();
    int lane = threadIdx.x & 63;
    int ch   = blockIdx.x * 256 + threadIdx.x;
    bool oob = (ch >= NCHUNK);
    int che  = oob ? (NCHUNK - 1) : ch;

    unsigned int nzmask = 0;
    if (!oob) {
        if (fb) {
            uint4 u = *(const uint4*)((const unsigned short*)av + (size_t)che * 8);
            unsigned int w[4] = {u.x, u.y, u.z, u.w};
#pragma unroll
            for (int p = 0; p < 4; ++p) {
                if (w[p] & 0xFFFFu)  nzmask |= 1u << (2 * p);
                if (w[p] >> 16)      nzmask |= 1u << (2 * p + 1);
            }
        } else {
            const unsigned int* aw = (const unsigned int*)av + (size_t)che * 8;
            uint4 u0 = *(const uint4*)(aw);
            uint4 u1 = *(const uint4*)(aw + 4);
            unsigned int w[8] = {u0.x, u0.y, u0.z, u0.w, u1.x, u1.y, u1.z, u1.w};
#pragma unroll
            for (int p = 0; p < 8; ++p)
                if (w[p]) nzmask |= 1u << p;
        }
    }
    int n  = che / 750;              // row of this chunk
    int m0 = (che - n * 750) * 8;    // first column of this chunk
    int c  = __popc(nzmask);

    // wave-wide exclusive prefix of c
    int p = c;
#pragma unroll
    for (int off = 1; off < 64; off <<= 1) {
        int t = __shfl_up(p, off);
        if (lane >= off) p += t;
    }
    int excl  = p - c;
    int total = __shfl(p, 63);

    int nFirst = __shfl(n, 0);
    int nLast  = __shfl(n, 63);
    unsigned long long mb = __ballot(n == nLast);
    int s0  = __ffsll(mb) - 1;       // first lane of the nLast segment
    int pS0 = __shfl(excl, s0);      // prefix at segment start

    int baseB = 0;
    if (lane == s0) {
        int totalB = total - pS0;
        if (totalB > 0) baseB = atomicAdd(rcur + nLast, totalB);
    }
    baseB = __shfl(baseB, s0);
    int baseA = 0;
    if (s0 > 0) {                    // wave straddles two rows
        if (lane == 0 && pS0 > 0) baseA = atomicAdd(rcur + nFirst, pS0);
        baseA = __shfl(baseA, 0);
    }

    int myOff = (n == nLast) ? (baseB + excl - pS0) : (baseA + excl);
    if (c) {
        int* dst = csr + (size_t)n * CAP;
        int w = 0;
#pragma unroll
        for (int pb = 0; pb < 8; ++pb) {
            if (nzmask & (1u << pb)) {
                int idx = myOff + (w++);
                if (idx < CAP) dst[idx] = m0 + pb;
            }
        }
    }
}

// ---------------- CSC (column lists) from CSR --------------------------------
__global__ __launch_bounds__(256)
void csc_kernel(const int* __restrict__ rcnt, const int* __restrict__ csr,
                int* __restrict__ ccur, int* __restrict__ csc)
{
    int tid = blockIdx.x * 256 + threadIdx.x;    // n*CAP + j
    int n = tid >> 7, j = tid & (CAP - 1);
    if (n >= NROW) return;
    int cnt = rcnt[n]; if (cnt > CAP) cnt = CAP;
    if (j >= cnt) return;
    int m = csr[(size_t)n * CAP + j];
    int slot = atomicAdd(ccur + m, 1);
    if (slot < CAP) csc[(size_t)m * CAP + slot] = n;
}

// ---------------- sparse-corrected attention (both directions) ---------------
// Exact softmax over 6000 kv entries: masked-out entries share weight e^-M/Z.
__global__ __launch_bounds__(256)
void attn_kernel(const float* __restrict__ Q, const float* __restrict__ Kbar,
                 const bf16_t* __restrict__ V, const float* __restrict__ Vsum,
                 const int* __restrict__ rcnt, const int* __restrict__ ccnt,
                 const int* __restrict__ csr, const int* __restrict__ csc,
                 bf16_t* __restrict__ att)
{
    __shared__ float qs[HID];
    __shared__ int   ml[CAP];
    __shared__ float sc[CAP * 5];    // [j][head], stride 5 vs bank conflicts
    __shared__ float w0s[NHEAD];

    int dir = blockIdx.y;            // 0: kg1 queries / kg2 kv ; 1: reverse
    int n   = blockIdx.x;
    int t   = threadIdx.x;
    int head = t >> 6, l = t & 63;

    size_t qrow = (size_t)(dir ? NROW + n : n);
    const float*  kb_base = Kbar + (dir ? 0 : (size_t)NROW * HD);
    const bf16_t* v_base  = V    + (dir ? 0 : (size_t)NROW * HID);
    const float*  vs      = Vsum + (dir ? 0 : HID);
    const int*    lst     = (dir ? csc : csr) + (size_t)n * CAP;
    int cnt = (dir ? ccnt : rcnt)[n];
    if (cnt > CAP) cnt = CAP;

    qs[t] = Q[qrow * HID + t];
    for (int j = t; j < cnt; j += 256) ml[j] = lst[j];
    __syncthreads();

    // phase 1: scores s[j][head] = SCALE * dot64(q_head, Kbar[m_j])
    for (int jb2 = 0; jb2 < cnt; jb2 += 64) {
        int j = jb2 + l;
        if (j < cnt) {
            int m = ml[j];
            const float* kb = kb_base + (size_t)m * HD;
            const float* qh = qs + head * HD;
            float dot = 0.f;
#pragma unroll
            for (int d = 0; d < HD; d += 4) {
                f32x4 k4 = *(const f32x4*)(kb + d);
                dot += qh[d] * k4[0] + qh[d+1] * k4[1] + qh[d+2] * k4[2] + qh[d+3] * k4[3];
            }
            sc[j * 5 + head] = dot * ATT_SCALE;
        }
    }
    __syncthreads();

    // phase 2: per-head exact softmax stats; wave `head` owns head `head`
    {
        float M = 0.0f;              // zero-score baseline always present
        for (int j = l; j < cnt; j += 64) M = fmaxf(M, sc[j * 5 + head]);
        for (int off = 32; off; off >>= 1) M = fmaxf(M, __shfl_xor(M, off));
        float e0 = __expf(-M);
        float e[2]; int k = 0;
        float S = 0.f;
        for (int j = l; j < cnt; j += 64, ++k) { e[k] = __expf(sc[j * 5 + head] - M); S += e[k]; }
        for (int off = 32; off; off >>= 1) S += __shfl_xor(S, off);
        float Z = S + (float)(NROW - cnt) * e0;
        float invZ = 1.0f / Z;
        k = 0;
        for (int j = l; j < cnt; j += 64, ++k) sc[j * 5 + head] = (e[k] - e0) * invZ;
        if (l == 0) w0s[head] = e0 * invZ;
    }
    __syncthreads();

    // phase 3: out[head][d] = w0*Vsum + sum_j coef_j * V[m_j][head*64+d]
    // 4-deep unroll keeps 4 gathers in flight.
    float acc = w0s[head] * vs[head * HD + l];
    int j = 0;
    for (; j + 4 <= cnt; j += 4) {
        float c0 = sc[(j+0) * 5 + head]; int m0 = ml[j+0];
        float c1 = sc[(j+1) * 5 + head]; int m1 = ml[j+1];
        float c2 = sc[(j+2) * 5 + head]; int m2 = ml[j+2];
        float c3 = sc[(j+3) * 5 + head]; int m3 = ml[j+3];
        float v0 = (float)v_base[(size_t)m0 * HID + head * HD + l];
        float v1 = (float)v_base[(size_t)m1 * HID + head * HD + l];
        float v2 = (float)v_base[(size_t)m2 * HID + head * HD + l];
        float v3 = (float)v_base[(size_t)m3 * HID + head * HD + l];
        acc += c0 * v0 + c1 * v1 + c2 * v2 + c3 * v3;
    }
    for (; j < cnt; ++j)
        acc += sc[j * 5 + head] * (float)v_base[(size_t)ml[j] * HID + head * HD + l];

    att[qrow * HID + head * HD + l] = (bf16_t)acc;
}

// ---------------- final projection + residual (dual dtype I/O) ---------------
__global__ __launch_bounds__(256)
void proj_out_kernel(const bf16_t* __restrict__ att, const bf16_t* __restrict__ wo,
                     const bf16_t* __restrict__ bo,
                     const void* __restrict__ e1v, const void* __restrict__ e2v,
                     void* __restrict__ outv, const int* __restrict__ flag)
{
    __shared__ int fb;
    if (threadIdx.x == 0) fb = *flag;
    __syncthreads();

    int m0   = blockIdx.x * 64;
    int n0   = blockIdx.y * 64;      // in [0,256)
    int wave = threadIdx.x >> 6;
    int lane = threadIdx.x & 63;
    int r16  = lane & 15;
    int quad = lane >> 4;

    int arow = m0 + wave * 16 + r16;
    int rr   = arow < MTOT ? arow : MTOT - 1;
    const bf16_t* asrc = att + (size_t)rr * HID;

    f32x4 acc0 = {0,0,0,0}, acc1 = {0,0,0,0}, acc2 = {0,0,0,0}, acc3 = {0,0,0,0};
#pragma unroll
    for (int kk = 0; kk < HID; kk += 32) {
        bf16x8 a = *(const bf16x8*)(asrc + kk + quad * 8);
        const bf16_t* b0 = wo + (size_t)(n0 + r16) * HID + kk + quad * 8;
        bf16x8 f0 = *(const bf16x8*)(b0);
        bf16x8 f1 = *(const bf16x8*)(b0 + 16 * HID);
        bf16x8 f2 = *(const bf16x8*)(b0 + 32 * HID);
        bf16x8 f3 = *(const bf16x8*)(b0 + 48 * HID);
        acc0 = __builtin_amdgcn_mfma_f32_16x16x32_bf16(a, f0, acc0, 0, 0, 0);
        acc1 = __builtin_amdgcn_mfma_f32_16x16x32_bf16(a, f1, acc1, 0, 0, 0);
        acc2 = __builtin_amdgcn_mfma_f32_16x16x32_bf16(a, f2, acc2, 0, 0, 0);
        acc3 = __builtin_amdgcn_mfma_f32_16x16x32_bf16(a, f3, acc3, 0, 0, 0);
    }
    f32x4 accs[4] = {acc0, acc1, acc2, acc3};
    int rbase = m0 + wave * 16 + quad * 4;
#pragma unroll
    for (int nt = 0; nt < 4; ++nt) {
        int j = n0 + nt * 16 + r16;
        float bb = (float)bo[j];
#pragma unroll
        for (int rg = 0; rg < 4; ++rg) {
            int r = rbase + rg;
            if (r < MTOT) {
                const void* eb = (r < NROW) ? e1v : e2v;
                size_t eidx = (size_t)((r < NROW) ? r : r - NROW) * HID + j;
                float ev = fb ? (float)((const bf16_t*)eb)[eidx]
                              : ((const float*)eb)[eidx];
                float v = accs[nt][rg] + bb + ev;
                size_t oidx = (size_t)r * HID + j;
                if (fb) ((bf16_t*)outv)[oidx] = (bf16_t)v;
                else    ((float*)outv)[oidx]  = v;
            }
        }
    }
}

// ---------------- host launcher ----------------------------------------------
extern "C" void kernel_launch(void* const* d_in, const int* in_sizes, int n_in,
                              void* d_out, int out_size, void* d_ws, size_t ws_size,
                              hipStream_t stream)
{
    const void* e1v = d_in[0];
    const void* e2v = d_in[1];
    const void* alv = d_in[2];
    const void* wqv = d_in[3];
    const void* bqv = d_in[4];
    const void* wkv = d_in[5];
    const void* bkv = d_in[6];
    const void* wvv = d_in[7];
    const void* bvv = d_in[8];
    const void* wov = d_in[9];
    const void* bov = d_in[10];

    size_t off = 0;
    char* base = (char*)d_ws;
    auto alloc = [&](size_t bytes) -> void* {
        void* p = base + off;
        off += (bytes + 255) & ~(size_t)255;
        return p;
    };
    float*  Q    = (float*) alloc((size_t)MTOT * HID * 4);
    float*  Kf   = (float*) alloc((size_t)MTOT * HID * 4);
    bf16_t* V    = (bf16_t*)alloc((size_t)MTOT * HID * 2);
    float*  Kbar = (float*) alloc((size_t)MTOT * HD * 4);
    bf16_t* att  = (bf16_t*)alloc((size_t)MTOT * HID * 2);
    bf16_t* cE   = (bf16_t*)alloc((size_t)MTOT * HID * 2);      // canon e1|e2
    bf16_t* cWB  = (bf16_t*)alloc((size_t)(4 * HID * HID + 4 * HID) * 2);
    int*    csr  = (int*)   alloc((size_t)NROW * CAP * 4);
    int*    csc  = (int*)   alloc((size_t)NROW * CAP * 4);
    // zeroed region: flag | rcur | ccur | Vsum (contiguous)
    int*    flag = (int*)   alloc(256);
    int*    rcur = (int*)   alloc(NROW * 4);
    int*    ccur = (int*)   alloc(NROW * 4);
    float*  Vsum = (float*) alloc(2 * HID * 4);

    bf16_t* cWq = cWB;
    bf16_t* cWk = cWB + 1 * HID * HID;
    bf16_t* cWv = cWB + 2 * HID * HID;
    bf16_t* cWo = cWB + 3 * HID * HID;
    bf16_t* cB  = cWB + 4 * HID * HID;                          // bq|bk|bv|bo

    size_t zero_bytes = (size_t)((char*)Vsum - (char*)flag) + 2 * HID * 4;
    hipMemsetAsync(flag, 0, zero_bytes, stream);

    // dtype detection from alignment matrix bit patterns
    detect_kernel<<<1, 256, 0, stream>>>((const unsigned short*)alv, flag);

    // canonicalize inputs to bf16 (2 launches)
    const int NE2 = 2 * NROW * HID;
    canon_emb_kernel<<<(NE2 + 255) / 256, 256, 0, stream>>>(e1v, e2v, cE, flag);
    const int NWB = 4 * HID * HID + 4 * HID;
    canon_wb_kernel<<<(NWB + 255) / 256, 256, 0, stream>>>(
        wqv, wkv, wvv, wov, bqv, bkv, bvv, bov, cWB, flag);

    // projections
    proj_qkv_kernel<<<dim3(188, 12), 256, 0, stream>>>(
        cE, cWq, cWk, cWv, cB, cB + HID, cB + 2 * HID, Q, Kf, V);
    kbar_kernel<<<(MTOT * HD + 255) / 256, 256, 0, stream>>>(Kf, Kbar);
    vsum_kernel<<<dim3(2, 24), 256, 0, stream>>>(V, Vsum);

    // sparse structure: single scan (row lists) + tiny CSC pass (col lists)
    scan_nz_kernel<<<(NCHUNK + 255) / 256, 256, 0, stream>>>(alv, rcur, csr, flag);
    csc_kernel<<<(NROW * CAP) / 256, 256, 0, stream>>>(rcur, csr, ccur, csc);

    // attention, both directions in one launch
    attn_kernel<<<dim3(NROW, 2), 256, 0, stream>>>(
        Q, Kbar, V, Vsum, rcur, ccur, csr, csc, att);

    // final projection + residual, both graphs
    proj_out_kernel<<<dim3(188, 4), 256, 0, stream>>>(
        att, cWo, cB + 3 * HID, e1v, e2v, d_out, flag);
}

// Round 4
// 421.901 us; speedup vs baseline: 1.8346x; 1.3266x over previous
//
#include <hip/hip_runtime.h>
#include <hip/hip_bf16.h>
#include <stdint.h>

typedef __bf16 bf16_t;
typedef __bf16 bf16x8 __attribute__((ext_vector_type(8)));
typedef __bf16 bf16x4 __attribute__((ext_vector_type(4)));
typedef float f32x4 __attribute__((ext_vector_type(4)));

#define NROW 6000           // rows of each graph
#define HID 256
#define NHEAD 4
#define HD 64
#define ATT_SCALE 0.125f    // HEAD_DIM^-0.5 = 1/8
#define MTOT 12000          // both graphs concatenated
#define CAP 128             // ELL capacity; Binom(6000,0.01) mean 60 sd 7.7
#define NCHUNK 4500000      // 6000*6000/8 ; 750 chunks per row exactly

// ---------------- dtype detection -------------------------------------------
// alignment_matrix holds exactly {0.0,1.0}. f32 -> even halfwords all 0x0000;
// bf16 -> ~1% of even halfwords are 0x3F80.
__global__ __launch_bounds__(256)
void detect_kernel(const unsigned short* __restrict__ a, int* __restrict__ flag)
{
    int k = blockIdx.x * 256 + threadIdx.x;
    int found = (k < 102400 && a[2 * k] != 0) ? 1 : 0;
    if (__ballot(found)) {
        if ((threadIdx.x & 63) == 0) atomicOr(flag, 1);
    }
}

// ---------------- canonicalize all dense inputs to bf16 ----------------------
// cE: e1|e2 (2*1.536M) ; cWB: Wq|Wk|Wv|Wo (4*65536) then bq|bk|bv|bo (4*256)
__global__ __launch_bounds__(256)
void canon_all_kernel(const void* __restrict__ e1, const void* __restrict__ e2,
                      const void* __restrict__ wq, const void* __restrict__ wk,
                      const void* __restrict__ wv, const void* __restrict__ wo,
                      const void* __restrict__ bq, const void* __restrict__ bk,
                      const void* __restrict__ bv, const void* __restrict__ bo,
                      bf16_t* __restrict__ cE, bf16_t* __restrict__ cWB,
                      const int* __restrict__ flag)
{
    __shared__ int fb;
    if (threadIdx.x == 0) fb = *flag;
    __syncthreads();
    int i = blockIdx.x * 256 + threadIdx.x;
    const int NE = NROW * HID;              // 1,536,000
    const int NW = 4 * HID * HID;           // 262,144
    auto conv = [&](const void* s, int k) -> bf16_t {
        return fb ? ((const bf16_t*)s)[k] : (bf16_t)(((const float*)s)[k]);
    };
    if (i < 2 * NE) {
        cE[i] = (i < NE) ? conv(e1, i) : conv(e2, i - NE);
        return;
    }
    i -= 2 * NE;
    if (i < NW) {
        int seg = i >> 16; int k = i & 65535;
        const void* s = (seg == 0) ? wq : (seg == 1) ? wk : (seg == 2) ? wv : wo;
        cWB[i] = conv(s, k);
        return;
    }
    i -= NW;
    if (i < 4 * HID) {
        int seg = i >> 8; int k = i & 255;
        const void* s = (seg == 0) ? bq : (seg == 1) ? bk : (seg == 2) ? bv : bo;
        cWB[NW + i] = conv(s, k);
    }
}

// ---------------- QKV projection: [12000,256] @ {Wq,Wk,Wv}^T + bias ----------
__global__ __launch_bounds__(256)
void proj_qkv_kernel(const bf16_t* __restrict__ e12,
                     const bf16_t* __restrict__ wq, const bf16_t* __restrict__ wk,
                     const bf16_t* __restrict__ wv,
                     const bf16_t* __restrict__ bq, const bf16_t* __restrict__ bk,
                     const bf16_t* __restrict__ bv,
                     float* __restrict__ Q, bf16_t* __restrict__ Kf, bf16_t* __restrict__ V)
{
    int m0   = blockIdx.x * 64;
    int n0   = blockIdx.y * 64;      // global output col in [0,768)
    int wave = threadIdx.x >> 6;
    int lane = threadIdx.x & 63;
    int r16  = lane & 15;
    int quad = lane >> 4;

    int sel = n0 >> 8;               // 0=Q, 1=K, 2=V
    int jb  = n0 & 255;
    const bf16_t* W; const bf16_t* bias;
    if (sel == 0)      { W = wq; bias = bq; }
    else if (sel == 1) { W = wk; bias = bk; }
    else               { W = wv; bias = bv; }

    int arow = m0 + wave * 16 + r16;
    int rr   = arow < MTOT ? arow : MTOT - 1;
    const bf16_t* asrc = e12 + (size_t)rr * HID;

    f32x4 acc0 = {0,0,0,0}, acc1 = {0,0,0,0}, acc2 = {0,0,0,0}, acc3 = {0,0,0,0};
#pragma unroll
    for (int kk = 0; kk < HID; kk += 32) {
        bf16x8 a = *(const bf16x8*)(asrc + kk + quad * 8);
        const bf16_t* b0 = W + (size_t)(jb + r16) * HID + kk + quad * 8;
        bf16x8 f0 = *(const bf16x8*)(b0);
        bf16x8 f1 = *(const bf16x8*)(b0 + 16 * HID);
        bf16x8 f2 = *(const bf16x8*)(b0 + 32 * HID);
        bf16x8 f3 = *(const bf16x8*)(b0 + 48 * HID);
        acc0 = __builtin_amdgcn_mfma_f32_16x16x32_bf16(a, f0, acc0, 0, 0, 0);
        acc1 = __builtin_amdgcn_mfma_f32_16x16x32_bf16(a, f1, acc1, 0, 0, 0);
        acc2 = __builtin_amdgcn_mfma_f32_16x16x32_bf16(a, f2, acc2, 0, 0, 0);
        acc3 = __builtin_amdgcn_mfma_f32_16x16x32_bf16(a, f3, acc3, 0, 0, 0);
    }
    f32x4 accs[4] = {acc0, acc1, acc2, acc3};
    int rbase = m0 + wave * 16 + quad * 4;
#pragma unroll
    for (int nt = 0; nt < 4; ++nt) {
        int j = jb + nt * 16 + r16;
        float bb = (float)bias[j];
#pragma unroll
        for (int rg = 0; rg < 4; ++rg) {
            int r = rbase + rg;
            if (r < MTOT) {
                float v = accs[nt][rg] + bb;
                if (sel == 0)      Q [(size_t)r * HID + j] = v;
                else if (sel == 1) Kf[(size_t)r * HID + j] = (bf16_t)v;
                else               V [(size_t)r * HID + j] = (bf16_t)v;
            }
        }
    }
}

// ---------------- fused: Kbar (bf16 head-mean of K) + Vsum -------------------
__global__ __launch_bounds__(256)
void kbar_vsum_kernel(const bf16_t* __restrict__ Kf, const bf16_t* __restrict__ V,
                      bf16_t* __restrict__ Kbar, float* __restrict__ Vsum)
{
    int b = blockIdx.x;
    if (b < 3000) {                       // Kbar: 12000*64 outputs
        int id = b * 256 + threadIdx.x;
        int m = id >> 6, d = id & 63;
        const bf16_t* kr = Kf + (size_t)m * HID + d;
        Kbar[id] = (bf16_t)(0.25f * ((float)kr[0] + (float)kr[64] +
                                     (float)kr[128] + (float)kr[192]));
    } else {                              // Vsum: 2 graphs x 24 segments
        int idx = b - 3000;               // 0..47
        int g = idx >> 5 ? 1 : (idx >= 24 ? 1 : 0); // idx/24
        g = idx / 24;
        int seg = idx - g * 24;
        int j = threadIdx.x;
        const bf16_t* base = V + ((size_t)(g * NROW + seg * 250)) * HID + j;
        float s = 0.f;
        for (int m = 0; m < 250; ++m) s += (float)base[(size_t)m * HID];
        atomicAdd(Vsum + g * HID + j, s);
    }
}

// ---------------- single-pass wave-aggregated ELL extraction -----------------
__global__ __launch_bounds__(256)
void scan_nz_kernel(const void* __restrict__ av,
                    int* __restrict__ rcur,           // [NROW] pre-zeroed
                    int* __restrict__ csr,            // [NROW*CAP]
                    const int* __restrict__ flag)
{
    __shared__ int fb;
    if (threadIdx.x == 0) fb = *flag;
    __syncthreads();
    int lane = threadIdx.x & 63;
    int ch   = blockIdx.x * 256 + threadIdx.x;
    bool oob = (ch >= NCHUNK);
    int che  = oob ? (NCHUNK - 1) : ch;

    unsigned int nzmask = 0;
    if (!oob) {
        if (fb) {
            uint4 u = *(const uint4*)((const unsigned short*)av + (size_t)che * 8);
            unsigned int w[4] = {u.x, u.y, u.z, u.w};
#pragma unroll
            for (int p = 0; p < 4; ++p) {
                if (w[p] & 0xFFFFu)  nzmask |= 1u << (2 * p);
                if (w[p] >> 16)      nzmask |= 1u << (2 * p + 1);
            }
        } else {
            const unsigned int* aw = (const unsigned int*)av + (size_t)che * 8;
            uint4 u0 = *(const uint4*)(aw);
            uint4 u1 = *(const uint4*)(aw + 4);
            unsigned int w[8] = {u0.x, u0.y, u0.z, u0.w, u1.x, u1.y, u1.z, u1.w};
#pragma unroll
            for (int p = 0; p < 8; ++p)
                if (w[p]) nzmask |= 1u << p;
        }
    }
    int n  = che / 750;              // row of this chunk
    int m0 = (che - n * 750) * 8;    // first column of this chunk
    int c  = __popc(nzmask);

    // wave-wide exclusive prefix of c
    int p = c;
#pragma unroll
    for (int off = 1; off < 64; off <<= 1) {
        int t = __shfl_up(p, off);
        if (lane >= off) p += t;
    }
    int excl  = p - c;
    int total = __shfl(p, 63);

    int nFirst = __shfl(n, 0);
    int nLast  = __shfl(n, 63);
    unsigned long long mb = __ballot(n == nLast);
    int s0  = __ffsll(mb) - 1;       // first lane of the nLast segment
    int pS0 = __shfl(excl, s0);

    int baseB = 0;
    if (lane == s0) {
        int totalB = total - pS0;
        if (totalB > 0) baseB = atomicAdd(rcur + nLast, totalB);
    }
    baseB = __shfl(baseB, s0);
    int baseA = 0;
    if (s0 > 0) {
        if (lane == 0 && pS0 > 0) baseA = atomicAdd(rcur + nFirst, pS0);
        baseA = __shfl(baseA, 0);
    }

    int myOff = (n == nLast) ? (baseB + excl - pS0) : (baseA + excl);
    if (c) {
        int* dst = csr + (size_t)n * CAP;
        int w = 0;
#pragma unroll
        for (int pb = 0; pb < 8; ++pb) {
            if (nzmask & (1u << pb)) {
                int idx = myOff + (w++);
                if (idx < CAP) dst[idx] = m0 + pb;
            }
        }
    }
}

// ---------------- CSC (column lists) from CSR --------------------------------
__global__ __launch_bounds__(256)
void csc_kernel(const int* __restrict__ rcnt, const int* __restrict__ csr,
                int* __restrict__ ccur, int* __restrict__ csc)
{
    int tid = blockIdx.x * 256 + threadIdx.x;    // n*CAP + j
    int n = tid >> 7, j = tid & (CAP - 1);
    if (n >= NROW) return;
    int cnt = rcnt[n]; if (cnt > CAP) cnt = CAP;
    if (j >= cnt) return;
    int m = csr[(size_t)n * CAP + j];
    int slot = atomicAdd(ccur + m, 1);
    if (slot < CAP) csc[(size_t)m * CAP + slot] = n;
}

// ---------------- sparse-corrected attention (both directions) ---------------
// Exact softmax over 6000 kv entries: masked-out entries share weight e^-M/Z.
// Phase1: Kbar rows staged to LDS (coalesced, XOR-rotated layout).
// Phase3: wave w owns j%4==w; lane = (head, 4 dims); 8B coalesced V loads.
__global__ __launch_bounds__(256)
void attn_kernel(const float* __restrict__ Q, const bf16_t* __restrict__ Kbar,
                 const bf16_t* __restrict__ V, const float* __restrict__ Vsum,
                 const int* __restrict__ rcnt, const int* __restrict__ ccnt,
                 const int* __restrict__ csr, const int* __restrict__ csc,
                 bf16_t* __restrict__ att)
{
    __shared__ float qs[HID];                    // 1 KB
    __shared__ int   ml[CAP];                    // 0.5 KB
    __shared__ float sc[CAP * 5];                // 2.5 KB, [j][head] stride 5
    __shared__ float w0s[NHEAD];
    __shared__ __align__(16) bf16_t kbs[CAP * HD]; // 16 KB; phase3 reuses as red[]

    int dir = blockIdx.y;
    int n   = blockIdx.x;
    int t   = threadIdx.x;
    int wave = t >> 6, lane = t & 63;

    size_t qrow = (size_t)(dir ? NROW + n : n);
    const bf16_t* kb_base = Kbar + (dir ? 0 : (size_t)NROW * HD);
    const bf16_t* v_base  = V    + (dir ? 0 : (size_t)NROW * HID);
    const float*  vs      = Vsum + (dir ? 0 : HID);
    const int*    lst     = (dir ? csc : csr) + (size_t)n * CAP;
    int cnt = (dir ? ccnt : rcnt)[n];
    if (cnt > CAP) cnt = CAP;

    qs[t] = Q[qrow * HID + t];
    for (int j = t; j < cnt; j += 256) ml[j] = lst[j];
    __syncthreads();

    // stage Kbar rows -> LDS, one coalesced 128B load per row per wave.
    // element d of row j stored at column ((d>>3 + j)&7)*8 + (d&7)  (chunk rotate)
    for (int j = wave; j < cnt; j += 4) {
        int m = ml[j];
        bf16_t v = kb_base[(size_t)m * HD + lane];
        kbs[j * HD + ((((lane >> 3) + j) & 7) << 3) + (lane & 7)] = v;
    }
    __syncthreads();

    // phase 1: scores s[j][head] = SCALE * dot64(q_head, Kbar[m_j]); head=wave
    {
        int head = wave;
        const float* qh = qs + head * HD;
        for (int jb2 = 0; jb2 < cnt; jb2 += 64) {
            int j = jb2 + lane;
            if (j < cnt) {
                float dot = 0.f;
#pragma unroll
                for (int c = 0; c < 8; ++c) {
                    bf16x8 k8 = *(const bf16x8*)(kbs + j * HD + (((c + j) & 7) << 3));
#pragma unroll
                    for (int i = 0; i < 8; ++i)
                        dot += qh[c * 8 + i] * (float)k8[i];
                }
                sc[j * 5 + head] = dot * ATT_SCALE;
            }
        }
    }
    __syncthreads();

    // phase 2: per-head exact softmax stats; wave `head` owns head `head`
    {
        int head = wave;
        float M = 0.0f;              // zero-score baseline always present
        for (int j = lane; j < cnt; j += 64) M = fmaxf(M, sc[j * 5 + head]);
        for (int off = 32; off; off >>= 1) M = fmaxf(M, __shfl_xor(M, off));
        float e0 = __expf(-M);
        float e[2]; int k = 0;
        float S = 0.f;
        for (int j = lane; j < cnt; j += 64, ++k) { e[k] = __expf(sc[j * 5 + head] - M); S += e[k]; }
        for (int off = 32; off; off >>= 1) S += __shfl_xor(S, off);
        float Z = S + (float)(NROW - cnt) * e0;
        float invZ = 1.0f / Z;
        k = 0;
        for (int j = lane; j < cnt; j += 64, ++k) sc[j * 5 + head] = (e[k] - e0) * invZ;
        if (lane == 0) w0s[head] = e0 * invZ;
    }
    __syncthreads();

    // phase 3: wave w handles j = w, w+4, ... ; lane covers (h3, d0=dq*4..+3)
    int h3 = lane >> 4;
    int dq = lane & 15;
    int colb = h3 * HD + dq * 4;                 // output col base for this lane
    float a0 = 0.f, a1 = 0.f, a2 = 0.f, a3 = 0.f;
    {
        int j = wave;
        for (; j + 4 < cnt; j += 8) {
            int   m0 = ml[j];            int   m1 = ml[j + 4];
            float c0 = sc[j * 5 + h3];   float c1 = sc[(j + 4) * 5 + h3];
            bf16x4 r0 = *(const bf16x4*)(v_base + (size_t)m0 * HID + colb);
            bf16x4 r1 = *(const bf16x4*)(v_base + (size_t)m1 * HID + colb);
            a0 += c0 * (float)r0[0] + c1 * (float)r1[0];
            a1 += c0 * (float)r0[1] + c1 * (float)r1[1];
            a2 += c0 * (float)r0[2] + c1 * (float)r1[2];
            a3 += c0 * (float)r0[3] + c1 * (float)r1[3];
        }
        if (j < cnt) {
            int   m0 = ml[j];
            float c0 = sc[j * 5 + h3];
            bf16x4 r0 = *(const bf16x4*)(v_base + (size_t)m0 * HID + colb);
            a0 += c0 * (float)r0[0];
            a1 += c0 * (float)r0[1];
            a2 += c0 * (float)r0[2];
            a3 += c0 * (float)r0[3];
        }
    }
    __syncthreads();                 // kbs reads done; reuse as reduction buf
    float* red = (float*)kbs;        // [4][256]
    red[wave * 256 + colb + 0] = a0;
    red[wave * 256 + colb + 1] = a1;
    red[wave * 256 + colb + 2] = a2;
    red[wave * 256 + colb + 3] = a3;
    __syncthreads();
    float tot = red[t] + red[256 + t] + red[512 + t] + red[768 + t]
              + w0s[t >> 6] * vs[t];
    att[qrow * HID + t] = (bf16_t)tot;
}

// ---------------- final projection + residual (dual dtype I/O) ---------------
__global__ __launch_bounds__(256)
void proj_out_kernel(const bf16_t* __restrict__ att, const bf16_t* __restrict__ wo,
                     const bf16_t* __restrict__ bo,
                     const void* __restrict__ e1v, const void* __restrict__ e2v,
                     void* __restrict__ outv, const int* __restrict__ flag)
{
    __shared__ int fb;
    if (threadIdx.x == 0) fb = *flag;
    __syncthreads();

    int m0   = blockIdx.x * 64;
    int n0   = blockIdx.y * 64;      // in [0,256)
    int wave = threadIdx.x >> 6;
    int lane = threadIdx.x & 63;
    int r16  = lane & 15;
    int quad = lane >> 4;

    int arow = m0 + wave * 16 + r16;
    int rr   = arow < MTOT ? arow : MTOT - 1;
    const bf16_t* asrc = att + (size_t)rr * HID;

    f32x4 acc0 = {0,0,0,0}, acc1 = {0,0,0,0}, acc2 = {0,0,0,0}, acc3 = {0,0,0,0};
#pragma unroll
    for (int kk = 0; kk < HID; kk += 32) {
        bf16x8 a = *(const bf16x8*)(asrc + kk + quad * 8);
        const bf16_t* b0 = wo + (size_t)(n0 + r16) * HID + kk + quad * 8;
        bf16x8 f0 = *(const bf16x8*)(b0);
        bf16x8 f1 = *(const bf16x8*)(b0 + 16 * HID);
        bf16x8 f2 = *(const bf16x8*)(b0 + 32 * HID);
        bf16x8 f3 = *(const bf16x8*)(b0 + 48 * HID);
        acc0 = __builtin_amdgcn_mfma_f32_16x16x32_bf16(a, f0, acc0, 0, 0, 0);
        acc1 = __builtin_amdgcn_mfma_f32_16x16x32_bf16(a, f1, acc1, 0, 0, 0);
        acc2 = __builtin_amdgcn_mfma_f32_16x16x32_bf16(a, f2, acc2, 0, 0, 0);
        acc3 = __builtin_amdgcn_mfma_f32_16x16x32_bf16(a, f3, acc3, 0, 0, 0);
    }
    f32x4 accs[4] = {acc0, acc1, acc2, acc3};
    int rbase = m0 + wave * 16 + quad * 4;
#pragma unroll
    for (int nt = 0; nt < 4; ++nt) {
        int j = n0 + nt * 16 + r16;
        float bb = (float)bo[j];
#pragma unroll
        for (int rg = 0; rg < 4; ++rg) {
            int r = rbase + rg;
            if (r < MTOT) {
                const void* eb = (r < NROW) ? e1v : e2v;
                size_t eidx = (size_t)((r < NROW) ? r : r - NROW) * HID + j;
                float ev = fb ? (float)((const bf16_t*)eb)[eidx]
                              : ((const float*)eb)[eidx];
                float v = accs[nt][rg] + bb + ev;
                size_t oidx = (size_t)r * HID + j;
                if (fb) ((bf16_t*)outv)[oidx] = (bf16_t)v;
                else    ((float*)outv)[oidx]  = v;
            }
        }
    }
}

// ---------------- host launcher ----------------------------------------------
extern "C" void kernel_launch(void* const* d_in, const int* in_sizes, int n_in,
                              void* d_out, int out_size, void* d_ws, size_t ws_size,
                              hipStream_t stream)
{
    const void* e1v = d_in[0];
    const void* e2v = d_in[1];
    const void* alv = d_in[2];
    const void* wqv = d_in[3];
    const void* bqv = d_in[4];
    const void* wkv = d_in[5];
    const void* bkv = d_in[6];
    const void* wvv = d_in[7];
    const void* bvv = d_in[8];
    const void* wov = d_in[9];
    const void* bov = d_in[10];

    size_t off = 0;
    char* base = (char*)d_ws;
    auto alloc = [&](size_t bytes) -> void* {
        void* p = base + off;
        off += (bytes + 255) & ~(size_t)255;
        return p;
    };
    float*  Q    = (float*) alloc((size_t)MTOT * HID * 4);
    bf16_t* Kf   = (bf16_t*)alloc((size_t)MTOT * HID * 2);
    bf16_t* V    = (bf16_t*)alloc((size_t)MTOT * HID * 2);
    bf16_t* Kbar = (bf16_t*)alloc((size_t)MTOT * HD * 2);
    bf16_t* att  = (bf16_t*)alloc((size_t)MTOT * HID * 2);
    bf16_t* cE   = (bf16_t*)alloc((size_t)MTOT * HID * 2);
    bf16_t* cWB  = (bf16_t*)alloc((size_t)(4 * HID * HID + 4 * HID) * 2);
    int*    csr  = (int*)   alloc((size_t)NROW * CAP * 4);
    int*    csc  = (int*)   alloc((size_t)NROW * CAP * 4);
    // zeroed region: flag | rcur | ccur | Vsum (contiguous)
    int*    flag = (int*)   alloc(256);
    int*    rcur = (int*)   alloc(NROW * 4);
    int*    ccur = (int*)   alloc(NROW * 4);
    float*  Vsum = (float*) alloc(2 * HID * 4);

    bf16_t* cWq = cWB;
    bf16_t* cWk = cWB + 1 * HID * HID;
    bf16_t* cWv = cWB + 2 * HID * HID;
    bf16_t* cWo = cWB + 3 * HID * HID;
    bf16_t* cB  = cWB + 4 * HID * HID;                          // bq|bk|bv|bo

    size_t zero_bytes = (size_t)((char*)Vsum - (char*)flag) + 2 * HID * 4;
    hipMemsetAsync(flag, 0, zero_bytes, stream);

    // dtype detection (parallel)
    detect_kernel<<<400, 256, 0, stream>>>((const unsigned short*)alv, flag);

    // canonicalize all inputs to bf16 (one launch)
    const int NTOTC = 2 * NROW * HID + 4 * HID * HID + 4 * HID;
    canon_all_kernel<<<(NTOTC + 255) / 256, 256, 0, stream>>>(
        e1v, e2v, wqv, wkv, wvv, wov, bqv, bkv, bvv, bov, cE, cWB, flag);

    // projections
    proj_qkv_kernel<<<dim3(188, 12), 256, 0, stream>>>(
        cE, cWq, cWk, cWv, cB, cB + HID, cB + 2 * HID, Q, Kf, V);
    kbar_vsum_kernel<<<3048, 256, 0, stream>>>(Kf, V, Kbar, Vsum);

    // sparse structure: single scan (row lists) + tiny CSC pass (col lists)
    scan_nz_kernel<<<(NCHUNK + 255) / 256, 256, 0, stream>>>(alv, rcur, csr, flag);
    csc_kernel<<<(NROW * CAP) / 256, 256, 0, stream>>>(rcur, csr, ccur, csc);

    // attention, both directions in one launch
    attn_kernel<<<dim3(NROW, 2), 256, 0, stream>>>(
        Q, Kbar, V, Vsum, rcur, ccur, csr, csc, att);

    // final projection + residual, both graphs
    proj_out_kernel<<<dim3(188, 4), 256, 0, stream>>>(
        att, cWo, cB + 3 * HID, e1v, e2v, d_out, flag);
}

// Round 8
// 421.113 us; speedup vs baseline: 1.8381x; 1.0019x over previous
//
#include <hip/hip_runtime.h>
#include <hip/hip_bf16.h>
#include <stdint.h>

typedef __bf16 bf16_t;
typedef __bf16 bf16x8 __attribute__((ext_vector_type(8)));
typedef __bf16 bf16x4 __attribute__((ext_vector_type(4)));
typedef float f32x4 __attribute__((ext_vector_type(4)));

#define NROW 6000           // rows of each graph
#define HID 256
#define NHEAD 4
#define HD 64
#define ATT_SCALE 0.125f    // HEAD_DIM^-0.5 = 1/8
#define MTOT 12000          // both graphs concatenated
#define CAP 128             // ELL capacity; Binom(6000,0.01) mean 60 sd 7.7
#define NCHUNK 4500000      // 6000*6000/8 ; 750 chunks of 8 f32 per row exactly

// ---------------- canonicalize weights f32 -> bf16 ---------------------------
// cW layout: Wq|Wk|Wv|Wo, 4*65536 elements.
__global__ __launch_bounds__(256)
void canon_w_kernel(const float* __restrict__ wq, const float* __restrict__ wk,
                    const float* __restrict__ wv, const float* __restrict__ wo,
                    bf16_t* __restrict__ cW)
{
    int i = blockIdx.x * 256 + threadIdx.x;      // [0, 262144)
    int seg = i >> 16, k = i & 65535;
    const float* s = (seg == 0) ? wq : (seg == 1) ? wk : (seg == 2) ? wv : wo;
    cW[i] = (bf16_t)s[k];
}

// ---------------- QKV projection: [12000,256] @ {Wq,Wk,Wv}^T + bias ----------
// A rows read as f32 and converted inline to bf16 MFMA fragments.
__global__ __launch_bounds__(256)
void proj_qkv_kernel(const float* __restrict__ e1, const float* __restrict__ e2,
                     const bf16_t* __restrict__ cW,
                     const float* __restrict__ bq, const float* __restrict__ bk,
                     const float* __restrict__ bv,
                     bf16_t* __restrict__ Q, bf16_t* __restrict__ Kf, bf16_t* __restrict__ V)
{
    int m0   = blockIdx.x * 64;
    int n0   = blockIdx.y * 64;      // global output col in [0,768)
    int wave = threadIdx.x >> 6;
    int lane = threadIdx.x & 63;
    int r16  = lane & 15;
    int quad = lane >> 4;

    int sel = n0 >> 8;               // 0=Q, 1=K, 2=V
    int jb  = n0 & 255;
    const bf16_t* W = cW + (size_t)sel * HID * HID;
    const float* bias = (sel == 0) ? bq : (sel == 1) ? bk : bv;

    int arow = m0 + wave * 16 + r16;
    int rr   = arow < MTOT ? arow : MTOT - 1;
    const float* asrc = (rr < NROW) ? (e1 + (size_t)rr * HID)
                                    : (e2 + (size_t)(rr - NROW) * HID);

    f32x4 acc0 = {0,0,0,0}, acc1 = {0,0,0,0}, acc2 = {0,0,0,0}, acc3 = {0,0,0,0};
#pragma unroll
    for (int kk = 0; kk < HID; kk += 32) {
        f32x4 af0 = *(const f32x4*)(asrc + kk + quad * 8);
        f32x4 af1 = *(const f32x4*)(asrc + kk + quad * 8 + 4);
        bf16x8 a;
#pragma unroll
        for (int i = 0; i < 4; ++i) { a[i] = (bf16_t)af0[i]; a[4 + i] = (bf16_t)af1[i]; }
        const bf16_t* b0 = W + (size_t)(jb + r16) * HID + kk + quad * 8;
        bf16x8 f0 = *(const bf16x8*)(b0);
        bf16x8 f1 = *(const bf16x8*)(b0 + 16 * HID);
        bf16x8 f2 = *(const bf16x8*)(b0 + 32 * HID);
        bf16x8 f3 = *(const bf16x8*)(b0 + 48 * HID);
        acc0 = __builtin_amdgcn_mfma_f32_16x16x32_bf16(a, f0, acc0, 0, 0, 0);
        acc1 = __builtin_amdgcn_mfma_f32_16x16x32_bf16(a, f1, acc1, 0, 0, 0);
        acc2 = __builtin_amdgcn_mfma_f32_16x16x32_bf16(a, f2, acc2, 0, 0, 0);
        acc3 = __builtin_amdgcn_mfma_f32_16x16x32_bf16(a, f3, acc3, 0, 0, 0);
    }
    f32x4 accs[4] = {acc0, acc1, acc2, acc3};
    bf16_t* dst = (sel == 0) ? Q : (sel == 1) ? Kf : V;
    int rbase = m0 + wave * 16 + quad * 4;
#pragma unroll
    for (int nt = 0; nt < 4; ++nt) {
        int j = jb + nt * 16 + r16;
        float bb = bias[j];
#pragma unroll
        for (int rg = 0; rg < 4; ++rg) {
            int r = rbase + rg;
            if (r < MTOT)
                dst[(size_t)r * HID + j] = (bf16_t)(accs[nt][rg] + bb);
        }
    }
}

// ---------------- fused: Kbar (bf16 head-mean of K) + Vsum -------------------
__global__ __launch_bounds__(256)
void kbar_vsum_kernel(const bf16_t* __restrict__ Kf, const bf16_t* __restrict__ V,
                      bf16_t* __restrict__ Kbar, float* __restrict__ Vsum)
{
    int b = blockIdx.x;
    if (b < 3000) {                       // Kbar: 12000*64 outputs
        int id = b * 256 + threadIdx.x;
        int m = id >> 6, d = id & 63;
        const bf16_t* kr = Kf + (size_t)m * HID + d;
        Kbar[id] = (bf16_t)(0.25f * ((float)kr[0] + (float)kr[64] +
                                     (float)kr[128] + (float)kr[192]));
    } else {                              // Vsum: 2 graphs x 24 segments of 250
        int idx = b - 3000;               // 0..47
        int g = idx / 24;
        int seg = idx - g * 24;
        int j = threadIdx.x;
        const bf16_t* base = V + ((size_t)(g * NROW + seg * 250)) * HID + j;
        float s = 0.f;
        for (int m = 0; m < 250; ++m) s += (float)base[(size_t)m * HID];
        atomicAdd(Vsum + g * HID + j, s);
    }
}

// ---------------- single-pass wave-aggregated ELL extraction (f32 input) -----
// Each lane owns 8 consecutive f32 elements (32 B); 750 chunks per row
// exactly, so a 64-lane wave straddles at most 2 rows.
__global__ __launch_bounds__(256)
void scan_nz_kernel(const float* __restrict__ am,
                    int* __restrict__ rcur,           // [NROW] pre-zeroed
                    int* __restrict__ csr)            // [NROW*CAP]
{
    int lane = threadIdx.x & 63;
    int ch   = blockIdx.x * 256 + threadIdx.x;
    bool oob = (ch >= NCHUNK);
    int che  = oob ? (NCHUNK - 1) : ch;

    unsigned int nzmask = 0;
    if (!oob) {
        const unsigned int* aw = (const unsigned int*)am + (size_t)che * 8;
        uint4 u0 = *(const uint4*)(aw);
        uint4 u1 = *(const uint4*)(aw + 4);
        unsigned int any = u0.x | u0.y | u0.z | u0.w | u1.x | u1.y | u1.z | u1.w;
        if (any) {
            unsigned int w[8] = {u0.x, u0.y, u0.z, u0.w, u1.x, u1.y, u1.z, u1.w};
#pragma unroll
            for (int p = 0; p < 8; ++p)
                if (w[p]) nzmask |= 1u << p;
        }
    }
    int n  = che / 750;              // row of this chunk
    int m0 = (che - n * 750) * 8;    // first column of this chunk
    int c  = __popc(nzmask);

    // wave-wide exclusive prefix of c
    int p = c;
#pragma unroll
    for (int off = 1; off < 64; off <<= 1) {
        int t = __shfl_up(p, off);
        if (lane >= off) p += t;
    }
    int excl  = p - c;
    int total = __shfl(p, 63);

    int nFirst = __shfl(n, 0);
    int nLast  = __shfl(n, 63);
    unsigned long long mb = __ballot(n == nLast);
    int s0  = __ffsll(mb) - 1;       // first lane of the nLast segment
    int pS0 = __shfl(excl, s0);

    int baseB = 0;
    if (lane == s0) {
        int totalB = total - pS0;
        if (totalB > 0) baseB = atomicAdd(rcur + nLast, totalB);
    }
    baseB = __shfl(baseB, s0);
    int baseA = 0;
    if (s0 > 0) {                    // wave straddles two rows
        if (lane == 0 && pS0 > 0) baseA = atomicAdd(rcur + nFirst, pS0);
        baseA = __shfl(baseA, 0);
    }

    int myOff = (n == nLast) ? (baseB + excl - pS0) : (baseA + excl);
    if (c) {
        int* dst = csr + (size_t)n * CAP;
        int w = 0;
#pragma unroll
        for (int pb = 0; pb < 8; ++pb) {
            if (nzmask & (1u << pb)) {
                int idx = myOff + (w++);
                if (idx < CAP) dst[idx] = m0 + pb;
            }
        }
    }
}

// ---------------- CSC (column lists) from CSR --------------------------------
__global__ __launch_bounds__(256)
void csc_kernel(const int* __restrict__ rcnt, const int* __restrict__ csr,
                int* __restrict__ ccur, int* __restrict__ csc)
{
    int tid = blockIdx.x * 256 + threadIdx.x;    // n*CAP + j
    int n = tid >> 7, j = tid & (CAP - 1);
    if (n >= NROW) return;
    int cnt = rcnt[n]; if (cnt > CAP) cnt = CAP;
    if (j >= cnt) return;
    int m = csr[(size_t)n * CAP + j];
    int slot = atomicAdd(ccur + m, 1);
    if (slot < CAP) csc[(size_t)m * CAP + slot] = n;
}

// ---------------- sparse-corrected attention (both directions) ---------------
// Exact softmax over 6000 kv entries: masked-out entries share weight e^-M/Z.
__global__ __launch_bounds__(256)
void attn_kernel(const bf16_t* __restrict__ Q, const bf16_t* __restrict__ Kbar,
                 const bf16_t* __restrict__ V, const float* __restrict__ Vsum,
                 const int* __restrict__ rcnt, const int* __restrict__ ccnt,
                 const int* __restrict__ csr, const int* __restrict__ csc,
                 bf16_t* __restrict__ att)
{
    __shared__ float qs[HID];                      // 1 KB
    __shared__ int   ml[CAP];                      // 0.5 KB
    __shared__ float sc[CAP * 5];                  // 2.5 KB, [j][head] stride 5
    __shared__ float w0s[NHEAD];
    __shared__ __align__(16) bf16_t kbs[CAP * HD]; // 16 KB; phase3 reuses as red[]

    int dir = blockIdx.y;
    int n   = blockIdx.x;
    int t   = threadIdx.x;
    int wave = t >> 6, lane = t & 63;

    size_t qrow = (size_t)(dir ? NROW + n : n);
    const bf16_t* kb_base = Kbar + (dir ? 0 : (size_t)NROW * HD);
    const bf16_t* v_base  = V    + (dir ? 0 : (size_t)NROW * HID);
    const float*  vs      = Vsum + (dir ? 0 : HID);
    const int*    lst     = (dir ? csc : csr) + (size_t)n * CAP;
    int cnt = (dir ? ccnt : rcnt)[n];
    if (cnt > CAP) cnt = CAP;

    qs[t] = (float)Q[qrow * HID + t];
    for (int j = t; j < cnt; j += 256) ml[j] = lst[j];
    __syncthreads();

    // stage Kbar rows -> LDS, one coalesced 128B load per row per wave.
    // element d of row j at column ((d>>3 + j)&7)*8 + (d&7)  (chunk rotate)
    for (int j = wave; j < cnt; j += 4) {
        int m = ml[j];
        bf16_t v = kb_base[(size_t)m * HD + lane];
        kbs[j * HD + ((((lane >> 3) + j) & 7) << 3) + (lane & 7)] = v;
    }
    __syncthreads();

    // phase 1: scores s[j][head] = SCALE * dot64(q_head, Kbar[m_j]); head=wave
    {
        int head = wave;
        const float* qh = qs + head * HD;
        for (int jb2 = 0; jb2 < cnt; jb2 += 64) {
            int j = jb2 + lane;
            if (j < cnt) {
                float dot = 0.f;
#pragma unroll
                for (int c = 0; c < 8; ++c) {
                    bf16x8 k8 = *(const bf16x8*)(kbs + j * HD + (((c + j) & 7) << 3));
#pragma unroll
                    for (int i = 0; i < 8; ++i)
                        dot += qh[c * 8 + i] * (float)k8[i];
                }
                sc[j * 5 + head] = dot * ATT_SCALE;
            }
        }
    }
    __syncthreads();

    // phase 2: per-head exact softmax stats; wave `head` owns head `head`
    {
        int head = wave;
        float M = 0.0f;              // zero-score baseline always present
        for (int j = lane; j < cnt; j += 64) M = fmaxf(M, sc[j * 5 + head]);
        for (int off = 32; off; off >>= 1) M = fmaxf(M, __shfl_xor(M, off));
        float e0 = __expf(-M);
        float e[2]; int k = 0;
        float S = 0.f;
        for (int j = lane; j < cnt; j += 64, ++k) { e[k] = __expf(sc[j * 5 + head] - M); S += e[k]; }
        for (int off = 32; off; off >>= 1) S += __shfl_xor(S, off);
        float Z = S + (float)(NROW - cnt) * e0;
        float invZ = 1.0f / Z;
        k = 0;
        for (int j = lane; j < cnt; j += 64, ++k) sc[j * 5 + head] = (e[k] - e0) * invZ;
        if (lane == 0) w0s[head] = e0 * invZ;
    }
    __syncthreads();

    // phase 3: wave w handles j = w, w+4, ...; lane covers (h3, 4 dims)
    int h3 = lane >> 4;
    int dq = lane & 15;
    int colb = h3 * HD + dq * 4;
    float a0 = 0.f, a1 = 0.f, a2 = 0.f, a3 = 0.f;
    {
        int j = wave;
        for (; j + 4 < cnt; j += 8) {
            int   m0 = ml[j];            int   m1 = ml[j + 4];
            float c0 = sc[j * 5 + h3];   float c1 = sc[(j + 4) * 5 + h3];
            bf16x4 r0 = *(const bf16x4*)(v_base + (size_t)m0 * HID + colb);
            bf16x4 r1 = *(const bf16x4*)(v_base + (size_t)m1 * HID + colb);
            a0 += c0 * (float)r0[0] + c1 * (float)r1[0];
            a1 += c0 * (float)r0[1] + c1 * (float)r1[1];
            a2 += c0 * (float)r0[2] + c1 * (float)r1[2];
            a3 += c0 * (float)r0[3] + c1 * (float)r1[3];
        }
        if (j < cnt) {
            int   m0 = ml[j];
            float c0 = sc[j * 5 + h3];
            bf16x4 r0 = *(const bf16x4*)(v_base + (size_t)m0 * HID + colb);
            a0 += c0 * (float)r0[0];
            a1 += c0 * (float)r0[1];
            a2 += c0 * (float)r0[2];
            a3 += c0 * (float)r0[3];
        }
    }
    __syncthreads();                 // kbs reads done; reuse as reduction buf
    float* red = (float*)kbs;        // [4][256]
    red[wave * 256 + colb + 0] = a0;
    red[wave * 256 + colb + 1] = a1;
    red[wave * 256 + colb + 2] = a2;
    red[wave * 256 + colb + 3] = a3;
    __syncthreads();
    float tot = red[t] + red[256 + t] + red[512 + t] + red[768 + t]
              + w0s[t >> 6] * vs[t];
    att[qrow * HID + t] = (bf16_t)tot;
}

// ---------------- final projection + residual (f32 everything, f32 out) ------
__global__ __launch_bounds__(256)
void proj_out_kernel(const bf16_t* __restrict__ att, const bf16_t* __restrict__ wo,
                     const float* __restrict__ bo,
                     const float* __restrict__ e1, const float* __restrict__ e2,
                     float* __restrict__ out)
{
    int m0   = blockIdx.x * 64;
    int n0   = blockIdx.y * 64;      // in [0,256)
    int wave = threadIdx.x >> 6;
    int lane = threadIdx.x & 63;
    int r16  = lane & 15;
    int quad = lane >> 4;

    int arow = m0 + wave * 16 + r16;
    int rr   = arow < MTOT ? arow : MTOT - 1;
    const bf16_t* asrc = att + (size_t)rr * HID;

    f32x4 acc0 = {0,0,0,0}, acc1 = {0,0,0,0}, acc2 = {0,0,0,0}, acc3 = {0,0,0,0};
#pragma unroll
    for (int kk = 0; kk < HID; kk += 32) {
        bf16x8 a = *(const bf16x8*)(asrc + kk + quad * 8);
        const bf16_t* b0 = wo + (size_t)(n0 + r16) * HID + kk + quad * 8;
        bf16x8 f0 = *(const bf16x8*)(b0);
        bf16x8 f1 = *(const bf16x8*)(b0 + 16 * HID);
        bf16x8 f2 = *(const bf16x8*)(b0 + 32 * HID);
        bf16x8 f3 = *(const bf16x8*)(b0 + 48 * HID);
        acc0 = __builtin_amdgcn_mfma_f32_16x16x32_bf16(a, f0, acc0, 0, 0, 0);
        acc1 = __builtin_amdgcn_mfma_f32_16x16x32_bf16(a, f1, acc1, 0, 0, 0);
        acc2 = __builtin_amdgcn_mfma_f32_16x16x32_bf16(a, f2, acc2, 0, 0, 0);
        acc3 = __builtin_amdgcn_mfma_f32_16x16x32_bf16(a, f3, acc3, 0, 0, 0);
    }
    f32x4 accs[4] = {acc0, acc1, acc2, acc3};
    int rbase = m0 + wave * 16 + quad * 4;
#pragma unroll
    for (int nt = 0; nt < 4; ++nt) {
        int j = n0 + nt * 16 + r16;
        float bb = bo[j];
#pragma unroll
        for (int rg = 0; rg < 4; ++rg) {
            int r = rbase + rg;
            if (r < MTOT) {
                const float* emb = (r < NROW) ? (e1 + (size_t)r * HID)
                                              : (e2 + (size_t)(r - NROW) * HID);
                float v = accs[nt][rg] + bb + emb[j];
                out[(size_t)r * HID + j] = v;        // f32 out; concat row r -> r*256
            }
        }
    }
}

// ---------------- host launcher ----------------------------------------------
extern "C" void kernel_launch(void* const* d_in, const int* in_sizes, int n_in,
                              void* d_out, int out_size, void* d_ws, size_t ws_size,
                              hipStream_t stream)
{
    const float* e1 = (const float*)d_in[0];
    const float* e2 = (const float*)d_in[1];
    const float* am = (const float*)d_in[2];
    const float* wq = (const float*)d_in[3];
    const float* bq = (const float*)d_in[4];
    const float* wk = (const float*)d_in[5];
    const float* bk = (const float*)d_in[6];
    const float* wv = (const float*)d_in[7];
    const float* bv = (const float*)d_in[8];
    const float* wo = (const float*)d_in[9];
    const float* bo = (const float*)d_in[10];
    float* out = (float*)d_out;

    size_t off = 0;
    char* base = (char*)d_ws;
    auto alloc = [&](size_t bytes) -> void* {
        void* p = base + off;
        off += (bytes + 255) & ~(size_t)255;
        return p;
    };
    bf16_t* Q    = (bf16_t*)alloc((size_t)MTOT * HID * 2);
    bf16_t* Kf   = (bf16_t*)alloc((size_t)MTOT * HID * 2);
    bf16_t* V    = (bf16_t*)alloc((size_t)MTOT * HID * 2);
    bf16_t* Kbar = (bf16_t*)alloc((size_t)MTOT * HD * 2);
    bf16_t* att  = (bf16_t*)alloc((size_t)MTOT * HID * 2);
    bf16_t* cW   = (bf16_t*)alloc((size_t)4 * HID * HID * 2);   // Wq|Wk|Wv|Wo bf16
    int*    csr  = (int*)   alloc((size_t)NROW * CAP * 4);
    int*    csc  = (int*)   alloc((size_t)NROW * CAP * 4);
    // zeroed region: rcur | ccur | Vsum (contiguous)
    int*    rcur = (int*)   alloc(NROW * 4);
    int*    ccur = (int*)   alloc(NROW * 4);
    float*  Vsum = (float*) alloc(2 * HID * 4);

    size_t zero_bytes = (size_t)((char*)Vsum - (char*)rcur) + 2 * HID * 4;
    hipMemsetAsync(rcur, 0, zero_bytes, stream);

    // weights f32 -> bf16 (1 MB total)
    canon_w_kernel<<<1024, 256, 0, stream>>>(wq, wk, wv, wo, cW);

    // QKV projection
    proj_qkv_kernel<<<dim3(188, 12), 256, 0, stream>>>(
        e1, e2, cW, bq, bk, bv, Q, Kf, V);

    // Kbar + Vsum
    kbar_vsum_kernel<<<3048, 256, 0, stream>>>(Kf, V, Kbar, Vsum);

    // sparse structure: single scan (row lists) + CSC pass (col lists)
    scan_nz_kernel<<<(NCHUNK + 255) / 256, 256, 0, stream>>>(am, rcur, csr);
    csc_kernel<<<(NROW * CAP) / 256, 256, 0, stream>>>(rcur, csr, ccur, csc);

    // attention, both directions
    attn_kernel<<<dim3(NROW, 2), 256, 0, stream>>>(
        Q, Kbar, V, Vsum, rcur, ccur, csr, csc, att);

    // final projection + residual (f32 output)
    proj_out_kernel<<<dim3(188, 4), 256, 0, stream>>>(att, cW + 3 * HID * HID, bo, e1, e2, out);
}

// Round 9
// 387.038 us; speedup vs baseline: 1.9999x; 1.0880x over previous
//
#include <hip/hip_runtime.h>
#include <hip/hip_bf16.h>
#include <stdint.h>

typedef __bf16 bf16_t;
typedef __bf16 bf16x8 __attribute__((ext_vector_type(8)));
typedef __bf16 bf16x4 __attribute__((ext_vector_type(4)));
typedef float f32x4 __attribute__((ext_vector_type(4)));

#define NROW 6000           // rows of each graph
#define HID 256
#define NHEAD 4
#define HD 64
#define ATT_SCALE 0.125f    // HEAD_DIM^-0.5 = 1/8
#define MTOT 12000          // both graphs concatenated
#define CAP 128             // ELL capacity; Binom(6000,0.01) mean 60 sd 7.7
#define NCHUNK 4500000      // 6000*6000/8 ; 750 chunks of 8 f32 per row exactly

// ---------------- canonicalize weights f32 -> bf16 ---------------------------
// cW layout: Wq|Wk|Wv|Wo, 4*65536 elements.
__global__ __launch_bounds__(256)
void canon_w_kernel(const float* __restrict__ wq, const float* __restrict__ wk,
                    const float* __restrict__ wv, const float* __restrict__ wo,
                    bf16_t* __restrict__ cW)
{
    int i = blockIdx.x * 256 + threadIdx.x;      // [0, 262144)
    int seg = i >> 16, k = i & 65535;
    const float* s = (seg == 0) ? wq : (seg == 1) ? wk : (seg == 2) ? wv : wo;
    cW[i] = (bf16_t)s[k];
}

// ---------------- QKV projection: [12000,256] @ {Wq,Wk,Wv}^T + bias ----------
// A rows read as f32 and converted inline to bf16 MFMA fragments.
__global__ __launch_bounds__(256)
void proj_qkv_kernel(const float* __restrict__ e1, const float* __restrict__ e2,
                     const bf16_t* __restrict__ cW,
                     const float* __restrict__ bq, const float* __restrict__ bk,
                     const float* __restrict__ bv,
                     bf16_t* __restrict__ Q, bf16_t* __restrict__ Kf, bf16_t* __restrict__ V)
{
    int m0   = blockIdx.x * 64;
    int n0   = blockIdx.y * 64;      // global output col in [0,768)
    int wave = threadIdx.x >> 6;
    int lane = threadIdx.x & 63;
    int r16  = lane & 15;
    int quad = lane >> 4;

    int sel = n0 >> 8;               // 0=Q, 1=K, 2=V
    int jb  = n0 & 255;
    const bf16_t* W = cW + (size_t)sel * HID * HID;
    const float* bias = (sel == 0) ? bq : (sel == 1) ? bk : bv;

    int arow = m0 + wave * 16 + r16;
    int rr   = arow < MTOT ? arow : MTOT - 1;
    const float* asrc = (rr < NROW) ? (e1 + (size_t)rr * HID)
                                    : (e2 + (size_t)(rr - NROW) * HID);

    f32x4 acc0 = {0,0,0,0}, acc1 = {0,0,0,0}, acc2 = {0,0,0,0}, acc3 = {0,0,0,0};
#pragma unroll
    for (int kk = 0; kk < HID; kk += 32) {
        f32x4 af0 = *(const f32x4*)(asrc + kk + quad * 8);
        f32x4 af1 = *(const f32x4*)(asrc + kk + quad * 8 + 4);
        bf16x8 a;
#pragma unroll
        for (int i = 0; i < 4; ++i) { a[i] = (bf16_t)af0[i]; a[4 + i] = (bf16_t)af1[i]; }
        const bf16_t* b0 = W + (size_t)(jb + r16) * HID + kk + quad * 8;
        bf16x8 f0 = *(const bf16x8*)(b0);
        bf16x8 f1 = *(const bf16x8*)(b0 + 16 * HID);
        bf16x8 f2 = *(const bf16x8*)(b0 + 32 * HID);
        bf16x8 f3 = *(const bf16x8*)(b0 + 48 * HID);
        acc0 = __builtin_amdgcn_mfma_f32_16x16x32_bf16(a, f0, acc0, 0, 0, 0);
        acc1 = __builtin_amdgcn_mfma_f32_16x16x32_bf16(a, f1, acc1, 0, 0, 0);
        acc2 = __builtin_amdgcn_mfma_f32_16x16x32_bf16(a, f2, acc2, 0, 0, 0);
        acc3 = __builtin_amdgcn_mfma_f32_16x16x32_bf16(a, f3, acc3, 0, 0, 0);
    }
    f32x4 accs[4] = {acc0, acc1, acc2, acc3};
    bf16_t* dst = (sel == 0) ? Q : (sel == 1) ? Kf : V;
    int rbase = m0 + wave * 16 + quad * 4;
#pragma unroll
    for (int nt = 0; nt < 4; ++nt) {
        int j = jb + nt * 16 + r16;
        float bb = bias[j];
#pragma unroll
        for (int rg = 0; rg < 4; ++rg) {
            int r = rbase + rg;
            if (r < MTOT)
                dst[(size_t)r * HID + j] = (bf16_t)(accs[nt][rg] + bb);
        }
    }
}

// ---------------- fused: Kbar (bf16 head-mean of K) + Vsum -------------------
__global__ __launch_bounds__(256)
void kbar_vsum_kernel(const bf16_t* __restrict__ Kf, const bf16_t* __restrict__ V,
                      bf16_t* __restrict__ Kbar, float* __restrict__ Vsum)
{
    int b = blockIdx.x;
    if (b < 3000) {                       // Kbar: 12000*64 outputs
        int id = b * 256 + threadIdx.x;
        int m = id >> 6, d = id & 63;
        const bf16_t* kr = Kf + (size_t)m * HID + d;
        Kbar[id] = (bf16_t)(0.25f * ((float)kr[0] + (float)kr[64] +
                                     (float)kr[128] + (float)kr[192]));
    } else {                              // Vsum: 2 graphs x 24 segments of 250
        int idx = b - 3000;               // 0..47
        int g = idx / 24;
        int seg = idx - g * 24;
        int j = threadIdx.x;
        const bf16_t* base = V + ((size_t)(g * NROW + seg * 250)) * HID + j;
        float s = 0.f;
        for (int m = 0; m < 250; ++m) s += (float)base[(size_t)m * HID];
        atomicAdd(Vsum + g * HID + j, s);
    }
}

// ---------------- single-pass wave-aggregated ELL extraction (f32 input) -----
// Each lane owns 8 consecutive f32 elements (32 B); 750 chunks per row
// exactly, so a 64-lane wave straddles at most 2 rows.
__global__ __launch_bounds__(256)
void scan_nz_kernel(const float* __restrict__ am,
                    int* __restrict__ rcur,           // [NROW] pre-zeroed
                    int* __restrict__ csr)            // [NROW*CAP]
{
    int lane = threadIdx.x & 63;
    int ch   = blockIdx.x * 256 + threadIdx.x;
    bool oob = (ch >= NCHUNK);
    int che  = oob ? (NCHUNK - 1) : ch;

    unsigned int nzmask = 0;
    if (!oob) {
        const unsigned int* aw = (const unsigned int*)am + (size_t)che * 8;
        uint4 u0 = *(const uint4*)(aw);
        uint4 u1 = *(const uint4*)(aw + 4);
        unsigned int any = u0.x | u0.y | u0.z | u0.w | u1.x | u1.y | u1.z | u1.w;
        if (any) {
            unsigned int w[8] = {u0.x, u0.y, u0.z, u0.w, u1.x, u1.y, u1.z, u1.w};
#pragma unroll
            for (int p = 0; p < 8; ++p)
                if (w[p]) nzmask |= 1u << p;
        }
    }
    int n  = che / 750;              // row of this chunk
    int m0 = (che - n * 750) * 8;    // first column of this chunk
    int c  = __popc(nzmask);

    // wave-wide exclusive prefix of c
    int p = c;
#pragma unroll
    for (int off = 1; off < 64; off <<= 1) {
        int t = __shfl_up(p, off);
        if (lane >= off) p += t;
    }
    int excl  = p - c;
    int total = __shfl(p, 63);

    int nFirst = __shfl(n, 0);
    int nLast  = __shfl(n, 63);
    unsigned long long mb = __ballot(n == nLast);
    int s0  = __ffsll(mb) - 1;       // first lane of the nLast segment
    int pS0 = __shfl(excl, s0);

    int baseB = 0;
    if (lane == s0) {
        int totalB = total - pS0;
        if (totalB > 0) baseB = atomicAdd(rcur + nLast, totalB);
    }
    baseB = __shfl(baseB, s0);
    int baseA = 0;
    if (s0 > 0) {                    // wave straddles two rows
        if (lane == 0 && pS0 > 0) baseA = atomicAdd(rcur + nFirst, pS0);
        baseA = __shfl(baseA, 0);
    }

    int myOff = (n == nLast) ? (baseB + excl - pS0) : (baseA + excl);
    if (c) {
        int* dst = csr + (size_t)n * CAP;
        int w = 0;
#pragma unroll
        for (int pb = 0; pb < 8; ++pb) {
            if (nzmask & (1u << pb)) {
                int idx = myOff + (w++);
                if (idx < CAP) dst[idx] = m0 + pb;
            }
        }
    }
}

// ---------------- CSC (column lists) from CSR --------------------------------
__global__ __launch_bounds__(256)
void csc_kernel(const int* __restrict__ rcnt, const int* __restrict__ csr,
                int* __restrict__ ccur, int* __restrict__ csc)
{
    int tid = blockIdx.x * 256 + threadIdx.x;    // n*CAP + j
    int n = tid >> 7, j = tid & (CAP - 1);
    if (n >= NROW) return;
    int cnt = rcnt[n]; if (cnt > CAP) cnt = CAP;
    if (j >= cnt) return;
    int m = csr[(size_t)n * CAP + j];
    int slot = atomicAdd(ccur + m, 1);
    if (slot < CAP) csc[(size_t)m * CAP + slot] = n;
}

// ---------------- sparse-corrected attention (both directions) ---------------
// Exact softmax over 6000 kv entries: masked-out entries share weight e^-M/Z.
// Phase 1 now on MFMA: scores = Kbar[rows]·q^T as 16x16x32 tiles, A-fragments
// gathered directly from global (16B/lane, native A layout), B = q row (bf16,
// LDS), heads in C columns 0..3.
__global__ __launch_bounds__(256)
void attn_kernel(const bf16_t* __restrict__ Q, const bf16_t* __restrict__ Kbar,
                 const bf16_t* __restrict__ V, const float* __restrict__ Vsum,
                 const int* __restrict__ rcnt, const int* __restrict__ ccnt,
                 const int* __restrict__ csr, const int* __restrict__ csc,
                 bf16_t* __restrict__ att)
{
    __shared__ __align__(16) bf16_t qsb[HID];      // 0.5 KB, q row in bf16
    __shared__ int   ml[CAP];                      // 0.5 KB
    __shared__ float sc[CAP * 5];                  // 2.5 KB, [j][head] stride 5
    __shared__ float w0s[NHEAD];
    __shared__ float red[4 * HID];                 // 4 KB cross-wave reduction

    int dir = blockIdx.y;
    int n   = blockIdx.x;
    int t   = threadIdx.x;
    int wave = t >> 6, lane = t & 63;

    size_t qrow = (size_t)(dir ? NROW + n : n);
    const bf16_t* kb_base = Kbar + (dir ? 0 : (size_t)NROW * HD);
    const bf16_t* v_base  = V    + (dir ? 0 : (size_t)NROW * HID);
    const float*  vs      = Vsum + (dir ? 0 : HID);
    const int*    lst     = (dir ? csc : csr) + (size_t)n * CAP;
    int cnt = (dir ? ccnt : rcnt)[n];
    if (cnt > CAP) cnt = CAP;

    qsb[t] = Q[qrow * HID + t];
    for (int j = t; j < cnt; j += 256) ml[j] = lst[j];
    __syncthreads();

    int m16  = lane & 15;
    int quad = lane >> 4;

    // phase 1 (MFMA): per 16-j tile, scores[j][head] = SCALE * Kbar[mj]·q_head
    {
        // B fragments: B[k][n=head] = q[head*64 + k]; zero for head >= 4
        bf16x8 b0, b1;
        if (m16 < NHEAD) {
            b0 = *(const bf16x8*)(qsb + m16 * HD + 0  + quad * 8);
            b1 = *(const bf16x8*)(qsb + m16 * HD + 32 + quad * 8);
        } else {
            b0 = (bf16x8)(bf16_t)0.f;
            b1 = (bf16x8)(bf16_t)0.f;
        }
        for (int jt = wave; jt * 16 < cnt; jt += 4) {
            int j  = jt * 16 + m16;
            int jj = j < cnt ? j : cnt - 1;           // clamp (cnt>0 here)
            int row = ml[jj];
            const bf16_t* ap = kb_base + (size_t)row * HD + quad * 8;
            bf16x8 a0 = *(const bf16x8*)(ap);
            bf16x8 a1 = *(const bf16x8*)(ap + 32);
            f32x4 acc = {0, 0, 0, 0};
            acc = __builtin_amdgcn_mfma_f32_16x16x32_bf16(a0, b0, acc, 0, 0, 0);
            acc = __builtin_amdgcn_mfma_f32_16x16x32_bf16(a1, b1, acc, 0, 0, 0);
            // C layout: col = lane&15 (head), row = quad*4 + rg (j within tile)
            if (m16 < NHEAD) {
#pragma unroll
                for (int rg = 0; rg < 4; ++rg) {
                    int jw = jt * 16 + quad * 4 + rg;
                    if (jw < cnt) sc[jw * 5 + m16] = acc[rg] * ATT_SCALE;
                }
            }
        }
    }
    __syncthreads();

    // phase 2: per-head exact softmax stats; wave `head` owns head `head`
    {
        int head = wave;
        float M = 0.0f;              // zero-score baseline always present
        for (int j = lane; j < cnt; j += 64) M = fmaxf(M, sc[j * 5 + head]);
        for (int off = 32; off; off >>= 1) M = fmaxf(M, __shfl_xor(M, off));
        float e0 = __expf(-M);
        float e[2]; int k = 0;
        float S = 0.f;
        for (int j = lane; j < cnt; j += 64, ++k) { e[k] = __expf(sc[j * 5 + head] - M); S += e[k]; }
        for (int off = 32; off; off >>= 1) S += __shfl_xor(S, off);
        float Z = S + (float)(NROW - cnt) * e0;
        float invZ = 1.0f / Z;
        k = 0;
        for (int j = lane; j < cnt; j += 64, ++k) sc[j * 5 + head] = (e[k] - e0) * invZ;
        if (lane == 0) w0s[head] = e0 * invZ;
    }
    __syncthreads();

    // phase 3: wave w handles j = w, w+4, ...; lane covers (h3, 4 dims)
    int h3 = lane >> 4;
    int dq = lane & 15;
    int colb = h3 * HD + dq * 4;
    float a0 = 0.f, a1 = 0.f, a2 = 0.f, a3 = 0.f;
    {
        int j = wave;
        for (; j + 4 < cnt; j += 8) {
            int   m0 = ml[j];            int   m1 = ml[j + 4];
            float c0 = sc[j * 5 + h3];   float c1 = sc[(j + 4) * 5 + h3];
            bf16x4 r0 = *(const bf16x4*)(v_base + (size_t)m0 * HID + colb);
            bf16x4 r1 = *(const bf16x4*)(v_base + (size_t)m1 * HID + colb);
            a0 += c0 * (float)r0[0] + c1 * (float)r1[0];
            a1 += c0 * (float)r0[1] + c1 * (float)r1[1];
            a2 += c0 * (float)r0[2] + c1 * (float)r1[2];
            a3 += c0 * (float)r0[3] + c1 * (float)r1[3];
        }
        if (j < cnt) {
            int   m0 = ml[j];
            float c0 = sc[j * 5 + h3];
            bf16x4 r0 = *(const bf16x4*)(v_base + (size_t)m0 * HID + colb);
            a0 += c0 * (float)r0[0];
            a1 += c0 * (float)r0[1];
            a2 += c0 * (float)r0[2];
            a3 += c0 * (float)r0[3];
        }
    }
    red[wave * 256 + colb + 0] = a0;
    red[wave * 256 + colb + 1] = a1;
    red[wave * 256 + colb + 2] = a2;
    red[wave * 256 + colb + 3] = a3;
    __syncthreads();
    float tot = red[t] + red[256 + t] + red[512 + t] + red[768 + t]
              + w0s[t >> 6] * vs[t];
    att[qrow * HID + t] = (bf16_t)tot;
}

// ---------------- final projection + residual (f32 everything, f32 out) ------
__global__ __launch_bounds__(256)
void proj_out_kernel(const bf16_t* __restrict__ att, const bf16_t* __restrict__ wo,
                     const float* __restrict__ bo,
                     const float* __restrict__ e1, const float* __restrict__ e2,
                     float* __restrict__ out)
{
    int m0   = blockIdx.x * 64;
    int n0   = blockIdx.y * 64;      // in [0,256)
    int wave = threadIdx.x >> 6;
    int lane = threadIdx.x & 63;
    int r16  = lane & 15;
    int quad = lane >> 4;

    int arow = m0 + wave * 16 + r16;
    int rr   = arow < MTOT ? arow : MTOT - 1;
    const bf16_t* asrc = att + (size_t)rr * HID;

    f32x4 acc0 = {0,0,0,0}, acc1 = {0,0,0,0}, acc2 = {0,0,0,0}, acc3 = {0,0,0,0};
#pragma unroll
    for (int kk = 0; kk < HID; kk += 32) {
        bf16x8 a = *(const bf16x8*)(asrc + kk + quad * 8);
        const bf16_t* b0 = wo + (size_t)(n0 + r16) * HID + kk + quad * 8;
        bf16x8 f0 = *(const bf16x8*)(b0);
        bf16x8 f1 = *(const bf16x8*)(b0 + 16 * HID);
        bf16x8 f2 = *(const bf16x8*)(b0 + 32 * HID);
        bf16x8 f3 = *(const bf16x8*)(b0 + 48 * HID);
        acc0 = __builtin_amdgcn_mfma_f32_16x16x32_bf16(a, f0, acc0, 0, 0, 0);
        acc1 = __builtin_amdgcn_mfma_f32_16x16x32_bf16(a, f1, acc1, 0, 0, 0);
        acc2 = __builtin_amdgcn_mfma_f32_16x16x32_bf16(a, f2, acc2, 0, 0, 0);
        acc3 = __builtin_amdgcn_mfma_f32_16x16x32_bf16(a, f3, acc3, 0, 0, 0);
    }
    f32x4 accs[4] = {acc0, acc1, acc2, acc3};
    int rbase = m0 + wave * 16 + quad * 4;
#pragma unroll
    for (int nt = 0; nt < 4; ++nt) {
        int j = n0 + nt * 16 + r16;
        float bb = bo[j];
#pragma unroll
        for (int rg = 0; rg < 4; ++rg) {
            int r = rbase + rg;
            if (r < MTOT) {
                const float* emb = (r < NROW) ? (e1 + (size_t)r * HID)
                                              : (e2 + (size_t)(r - NROW) * HID);
                float v = accs[nt][rg] + bb + emb[j];
                out[(size_t)r * HID + j] = v;        // f32 out; concat row r -> r*256
            }
        }
    }
}

// ---------------- host launcher ----------------------------------------------
extern "C" void kernel_launch(void* const* d_in, const int* in_sizes, int n_in,
                              void* d_out, int out_size, void* d_ws, size_t ws_size,
                              hipStream_t stream)
{
    const float* e1 = (const float*)d_in[0];
    const float* e2 = (const float*)d_in[1];
    const float* am = (const float*)d_in[2];
    const float* wq = (const float*)d_in[3];
    const float* bq = (const float*)d_in[4];
    const float* wk = (const float*)d_in[5];
    const float* bk = (const float*)d_in[6];
    const float* wv = (const float*)d_in[7];
    const float* bv = (const float*)d_in[8];
    const float* wo = (const float*)d_in[9];
    const float* bo = (const float*)d_in[10];
    float* out = (float*)d_out;

    size_t off = 0;
    char* base = (char*)d_ws;
    auto alloc = [&](size_t bytes) -> void* {
        void* p = base + off;
        off += (bytes + 255) & ~(size_t)255;
        return p;
    };
    bf16_t* Q    = (bf16_t*)alloc((size_t)MTOT * HID * 2);
    bf16_t* Kf   = (bf16_t*)alloc((size_t)MTOT * HID * 2);
    bf16_t* V    = (bf16_t*)alloc((size_t)MTOT * HID * 2);
    bf16_t* Kbar = (bf16_t*)alloc((size_t)MTOT * HD * 2);
    bf16_t* att  = (bf16_t*)alloc((size_t)MTOT * HID * 2);
    bf16_t* cW   = (bf16_t*)alloc((size_t)4 * HID * HID * 2);   // Wq|Wk|Wv|Wo bf16
    int*    csr  = (int*)   alloc((size_t)NROW * CAP * 4);
    int*    csc  = (int*)   alloc((size_t)NROW * CAP * 4);
    // zeroed region: rcur | ccur | Vsum (contiguous)
    int*    rcur = (int*)   alloc(NROW * 4);
    int*    ccur = (int*)   alloc(NROW * 4);
    float*  Vsum = (float*) alloc(2 * HID * 4);

    size_t zero_bytes = (size_t)((char*)Vsum - (char*)rcur) + 2 * HID * 4;
    hipMemsetAsync(rcur, 0, zero_bytes, stream);

    // weights f32 -> bf16 (1 MB total)
    canon_w_kernel<<<1024, 256, 0, stream>>>(wq, wk, wv, wo, cW);

    // QKV projection
    proj_qkv_kernel<<<dim3(188, 12), 256, 0, stream>>>(
        e1, e2, cW, bq, bk, bv, Q, Kf, V);

    // Kbar + Vsum
    kbar_vsum_kernel<<<3048, 256, 0, stream>>>(Kf, V, Kbar, Vsum);

    // sparse structure: single scan (row lists) + CSC pass (col lists)
    scan_nz_kernel<<<(NCHUNK + 255) / 256, 256, 0, stream>>>(am, rcur, csr);
    csc_kernel<<<(NROW * CAP) / 256, 256, 0, stream>>>(rcur, csr, ccur, csc);

    // attention, both directions
    attn_kernel<<<dim3(NROW, 2), 256, 0, stream>>>(
        Q, Kbar, V, Vsum, rcur, ccur, csr, csc, att);

    // final projection + residual (f32 output)
    proj_out_kernel<<<dim3(188, 4), 256, 0, stream>>>(att, cW + 3 * HID * HID, bo, e1, e2, out);
}

// Round 10
// 373.375 us; speedup vs baseline: 2.0731x; 1.0366x over previous
//
#include <hip/hip_runtime.h>
#include <hip/hip_bf16.h>
#include <stdint.h>

typedef __bf16 bf16_t;
typedef __bf16 bf16x8 __attribute__((ext_vector_type(8)));
typedef __bf16 bf16x4 __attribute__((ext_vector_type(4)));
typedef float f32x4 __attribute__((ext_vector_type(4)));

#define NROW 6000           // rows of each graph
#define HID 256
#define NHEAD 4
#define HD 64
#define ATT_SCALE 0.125f    // HEAD_DIM^-0.5 = 1/8
#define MTOT 12000          // both graphs concatenated
#define CAP 128             // ELL capacity; Binom(6000,0.01) mean 60 sd 7.7
#define NCH16 2250000       // 6000*6000/16 ; 375 chunks of 16 f32 per row exactly

#define CANON_BLOCKS 1024                       // 1024*256 = 262144 = 4*65536
#define SCAN_BLOCKS  ((NCH16 + 255) / 256)      // 8790
#define PROJ_BLOCKS  (188 * 12)                 // 2256
#define CSC_BLOCKS   ((NROW * CAP) / 256)       // 3000

// ============ L1: canon weights (f32->bf16)  ∥  16-wide align scan ===========
__global__ __launch_bounds__(256)
void l1_canon_scan(const float* __restrict__ wq, const float* __restrict__ wk,
                   const float* __restrict__ wv, const float* __restrict__ wo,
                   bf16_t* __restrict__ cW,
                   const float* __restrict__ am,
                   int* __restrict__ rcur,          // [NROW] pre-zeroed
                   int* __restrict__ csr)           // [NROW*CAP]
{
    if (blockIdx.x < CANON_BLOCKS) {
        // ---- canonicalize weights: cW = Wq|Wk|Wv|Wo ----
        int i = blockIdx.x * 256 + threadIdx.x;     // [0, 262144)
        int seg = i >> 16, k = i & 65535;
        const float* s = (seg == 0) ? wq : (seg == 1) ? wk : (seg == 2) ? wv : wo;
        cW[i] = (bf16_t)s[k];
        return;
    }
    // ---- scan: 16 f32 elements (64 B) per lane, wave-aggregated ELL ----
    int lane = threadIdx.x & 63;
    int ch   = (blockIdx.x - CANON_BLOCKS) * 256 + threadIdx.x;
    bool oob = (ch >= NCH16);
    int che  = oob ? (NCH16 - 1) : ch;

    unsigned int nzmask = 0;
    if (!oob) {
        const uint4* p4 = (const uint4*)((const unsigned int*)am + (size_t)che * 16);
        uint4 u0 = p4[0], u1 = p4[1], u2 = p4[2], u3 = p4[3];
        unsigned int any = u0.x | u0.y | u0.z | u0.w | u1.x | u1.y | u1.z | u1.w
                         | u2.x | u2.y | u2.z | u2.w | u3.x | u3.y | u3.z | u3.w;
        if (any) {
            unsigned int w[16] = {u0.x, u0.y, u0.z, u0.w, u1.x, u1.y, u1.z, u1.w,
                                  u2.x, u2.y, u2.z, u2.w, u3.x, u3.y, u3.z, u3.w};
#pragma unroll
            for (int p = 0; p < 16; ++p)
                if (w[p]) nzmask |= 1u << p;
        }
    }
    int n  = che / 375;              // row of this chunk
    int m0 = (che - n * 375) * 16;   // first column of this chunk
    int c  = __popc(nzmask);

    // wave-wide exclusive prefix of c
    int p = c;
#pragma unroll
    for (int off = 1; off < 64; off <<= 1) {
        int t = __shfl_up(p, off);
        if (lane >= off) p += t;
    }
    int excl  = p - c;
    int total = __shfl(p, 63);

    int nFirst = __shfl(n, 0);
    int nLast  = __shfl(n, 63);
    unsigned long long mb = __ballot(n == nLast);
    int s0  = __ffsll(mb) - 1;       // first lane of the nLast segment
    int pS0 = __shfl(excl, s0);

    int baseB = 0;
    if (lane == s0) {
        int totalB = total - pS0;
        if (totalB > 0) baseB = atomicAdd(rcur + nLast, totalB);
    }
    baseB = __shfl(baseB, s0);
    int baseA = 0;
    if (s0 > 0) {                    // wave straddles two rows
        if (lane == 0 && pS0 > 0) baseA = atomicAdd(rcur + nFirst, pS0);
        baseA = __shfl(baseA, 0);
    }

    int myOff = (n == nLast) ? (baseB + excl - pS0) : (baseA + excl);
    if (c) {
        int* dst = csr + (size_t)n * CAP;
        int w = 0;
#pragma unroll
        for (int pb = 0; pb < 16; ++pb) {
            if (nzmask & (1u << pb)) {
                int idx = myOff + (w++);
                if (idx < CAP) dst[idx] = m0 + pb;
            }
        }
    }
}

// ============ L2: QKV projection (MFMA)  ∥  CSC-from-CSR scatter =============
__global__ __launch_bounds__(256)
void l2_proj_csc(const float* __restrict__ e1, const float* __restrict__ e2,
                 const bf16_t* __restrict__ cW,
                 const float* __restrict__ bq, const float* __restrict__ bk,
                 const float* __restrict__ bv,
                 bf16_t* __restrict__ Q, bf16_t* __restrict__ Kf, bf16_t* __restrict__ V,
                 const int* __restrict__ rcnt, const int* __restrict__ csr,
                 int* __restrict__ ccur, int* __restrict__ csc)
{
    if (blockIdx.x >= PROJ_BLOCKS) {
        // ---- CSC scatter ----
        int tid = (blockIdx.x - PROJ_BLOCKS) * 256 + threadIdx.x;  // n*CAP + j
        int n = tid >> 7, j = tid & (CAP - 1);
        if (n >= NROW) return;
        int cnt = rcnt[n]; if (cnt > CAP) cnt = CAP;
        if (j >= cnt) return;
        int m = csr[(size_t)n * CAP + j];
        int slot = atomicAdd(ccur + m, 1);
        if (slot < CAP) csc[(size_t)m * CAP + slot] = n;
        return;
    }
    // ---- projection: [12000,256] @ {Wq,Wk,Wv}^T + bias ----
    int bx   = blockIdx.x;
    int m0   = (bx % 188) * 64;
    int n0   = (bx / 188) * 64;      // output col in [0,768)
    int wave = threadIdx.x >> 6;
    int lane = threadIdx.x & 63;
    int r16  = lane & 15;
    int quad = lane >> 4;

    int sel = n0 >> 8;               // 0=Q, 1=K, 2=V
    int jb  = n0 & 255;
    const bf16_t* W = cW + (size_t)sel * HID * HID;
    const float* bias = (sel == 0) ? bq : (sel == 1) ? bk : bv;

    int arow = m0 + wave * 16 + r16;
    int rr   = arow < MTOT ? arow : MTOT - 1;
    const float* asrc = (rr < NROW) ? (e1 + (size_t)rr * HID)
                                    : (e2 + (size_t)(rr - NROW) * HID);

    f32x4 acc0 = {0,0,0,0}, acc1 = {0,0,0,0}, acc2 = {0,0,0,0}, acc3 = {0,0,0,0};
#pragma unroll
    for (int kk = 0; kk < HID; kk += 32) {
        f32x4 af0 = *(const f32x4*)(asrc + kk + quad * 8);
        f32x4 af1 = *(const f32x4*)(asrc + kk + quad * 8 + 4);
        bf16x8 a;
#pragma unroll
        for (int i = 0; i < 4; ++i) { a[i] = (bf16_t)af0[i]; a[4 + i] = (bf16_t)af1[i]; }
        const bf16_t* b0 = W + (size_t)(jb + r16) * HID + kk + quad * 8;
        bf16x8 f0 = *(const bf16x8*)(b0);
        bf16x8 f1 = *(const bf16x8*)(b0 + 16 * HID);
        bf16x8 f2 = *(const bf16x8*)(b0 + 32 * HID);
        bf16x8 f3 = *(const bf16x8*)(b0 + 48 * HID);
        acc0 = __builtin_amdgcn_mfma_f32_16x16x32_bf16(a, f0, acc0, 0, 0, 0);
        acc1 = __builtin_amdgcn_mfma_f32_16x16x32_bf16(a, f1, acc1, 0, 0, 0);
        acc2 = __builtin_amdgcn_mfma_f32_16x16x32_bf16(a, f2, acc2, 0, 0, 0);
        acc3 = __builtin_amdgcn_mfma_f32_16x16x32_bf16(a, f3, acc3, 0, 0, 0);
    }
    f32x4 accs[4] = {acc0, acc1, acc2, acc3};
    bf16_t* dst = (sel == 0) ? Q : (sel == 1) ? Kf : V;
    int rbase = m0 + wave * 16 + quad * 4;
#pragma unroll
    for (int nt = 0; nt < 4; ++nt) {
        int j = jb + nt * 16 + r16;
        float bb = bias[j];
#pragma unroll
        for (int rg = 0; rg < 4; ++rg) {
            int r = rbase + rg;
            if (r < MTOT)
                dst[(size_t)r * HID + j] = (bf16_t)(accs[nt][rg] + bb);
        }
    }
}

// ---------------- fused: Kbar (bf16 head-mean of K) + Vsum -------------------
__global__ __launch_bounds__(256)
void kbar_vsum_kernel(const bf16_t* __restrict__ Kf, const bf16_t* __restrict__ V,
                      bf16_t* __restrict__ Kbar, float* __restrict__ Vsum)
{
    int b = blockIdx.x;
    if (b < 3000) {                       // Kbar: 12000*64 outputs
        int id = b * 256 + threadIdx.x;
        int m = id >> 6, d = id & 63;
        const bf16_t* kr = Kf + (size_t)m * HID + d;
        Kbar[id] = (bf16_t)(0.25f * ((float)kr[0] + (float)kr[64] +
                                     (float)kr[128] + (float)kr[192]));
    } else {                              // Vsum: 2 graphs x 24 segments of 250
        int idx = b - 3000;               // 0..47
        int g = idx / 24;
        int seg = idx - g * 24;
        int j = threadIdx.x;
        const bf16_t* base = V + ((size_t)(g * NROW + seg * 250)) * HID + j;
        float s = 0.f;
        for (int m = 0; m < 250; ++m) s += (float)base[(size_t)m * HID];
        atomicAdd(Vsum + g * HID + j, s);
    }
}

// ---------------- sparse-corrected attention (both directions) ---------------
// Exact softmax over 6000 kv entries: masked-out entries share weight e^-M/Z.
// Phase 1 on MFMA: scores = Kbar[rows]·q^T, A-fragments gathered directly from
// global (16B/lane, native A layout), B = q row (bf16, LDS), heads in C cols.
__global__ __launch_bounds__(256)
void attn_kernel(const bf16_t* __restrict__ Q, const bf16_t* __restrict__ Kbar,
                 const bf16_t* __restrict__ V, const float* __restrict__ Vsum,
                 const int* __restrict__ rcnt, const int* __restrict__ ccnt,
                 const int* __restrict__ csr, const int* __restrict__ csc,
                 bf16_t* __restrict__ att)
{
    __shared__ __align__(16) bf16_t qsb[HID];      // 0.5 KB, q row in bf16
    __shared__ int   ml[CAP];                      // 0.5 KB
    __shared__ float sc[CAP * 5];                  // 2.5 KB, [j][head] stride 5
    __shared__ float w0s[NHEAD];
    __shared__ float red[4 * HID];                 // 4 KB cross-wave reduction

    int dir = blockIdx.y;
    int n   = blockIdx.x;
    int t   = threadIdx.x;
    int wave = t >> 6, lane = t & 63;

    size_t qrow = (size_t)(dir ? NROW + n : n);
    const bf16_t* kb_base = Kbar + (dir ? 0 : (size_t)NROW * HD);
    const bf16_t* v_base  = V    + (dir ? 0 : (size_t)NROW * HID);
    const float*  vs      = Vsum + (dir ? 0 : HID);
    const int*    lst     = (dir ? csc : csr) + (size_t)n * CAP;
    int cnt = (dir ? ccnt : rcnt)[n];
    if (cnt > CAP) cnt = CAP;

    qsb[t] = Q[qrow * HID + t];
    for (int j = t; j < cnt; j += 256) ml[j] = lst[j];
    __syncthreads();

    int m16  = lane & 15;
    int quad = lane >> 4;

    // phase 1 (MFMA): per 16-j tile, scores[j][head] = SCALE * Kbar[mj]·q_head
    {
        bf16x8 b0, b1;
        if (m16 < NHEAD) {
            b0 = *(const bf16x8*)(qsb + m16 * HD + 0  + quad * 8);
            b1 = *(const bf16x8*)(qsb + m16 * HD + 32 + quad * 8);
        } else {
            b0 = (bf16x8)(bf16_t)0.f;
            b1 = (bf16x8)(bf16_t)0.f;
        }
        for (int jt = wave; jt * 16 < cnt; jt += 4) {
            int j  = jt * 16 + m16;
            int jj = j < cnt ? j : cnt - 1;           // clamp (cnt>0 here)
            int row = ml[jj];
            const bf16_t* ap = kb_base + (size_t)row * HD + quad * 8;
            bf16x8 a0 = *(const bf16x8*)(ap);
            bf16x8 a1 = *(const bf16x8*)(ap + 32);
            f32x4 acc = {0, 0, 0, 0};
            acc = __builtin_amdgcn_mfma_f32_16x16x32_bf16(a0, b0, acc, 0, 0, 0);
            acc = __builtin_amdgcn_mfma_f32_16x16x32_bf16(a1, b1, acc, 0, 0, 0);
            // C layout: col = lane&15 (head), row = quad*4 + rg (j within tile)
            if (m16 < NHEAD) {
#pragma unroll
                for (int rg = 0; rg < 4; ++rg) {
                    int jw = jt * 16 + quad * 4 + rg;
                    if (jw < cnt) sc[jw * 5 + m16] = acc[rg] * ATT_SCALE;
                }
            }
        }
    }
    __syncthreads();

    // phase 2: per-head exact softmax stats; wave `head` owns head `head`
    {
        int head = wave;
        float M = 0.0f;              // zero-score baseline always present
        for (int j = lane; j < cnt; j += 64) M = fmaxf(M, sc[j * 5 + head]);
        for (int off = 32; off; off >>= 1) M = fmaxf(M, __shfl_xor(M, off));
        float e0 = __expf(-M);
        float e[2]; int k = 0;
        float S = 0.f;
        for (int j = lane; j < cnt; j += 64, ++k) { e[k] = __expf(sc[j * 5 + head] - M); S += e[k]; }
        for (int off = 32; off; off >>= 1) S += __shfl_xor(S, off);
        float Z = S + (float)(NROW - cnt) * e0;
        float invZ = 1.0f / Z;
        k = 0;
        for (int j = lane; j < cnt; j += 64, ++k) sc[j * 5 + head] = (e[k] - e0) * invZ;
        if (lane == 0) w0s[head] = e0 * invZ;
    }
    __syncthreads();

    // phase 3: wave w handles j = w, w+4, ...; lane covers (h3, 4 dims)
    int h3 = lane >> 4;
    int dq = lane & 15;
    int colb = h3 * HD + dq * 4;
    float a0 = 0.f, a1 = 0.f, a2 = 0.f, a3 = 0.f;
    {
        int j = wave;
        for (; j + 4 < cnt; j += 8) {
            int   m0 = ml[j];            int   m1 = ml[j + 4];
            float c0 = sc[j * 5 + h3];   float c1 = sc[(j + 4) * 5 + h3];
            bf16x4 r0 = *(const bf16x4*)(v_base + (size_t)m0 * HID + colb);
            bf16x4 r1 = *(const bf16x4*)(v_base + (size_t)m1 * HID + colb);
            a0 += c0 * (float)r0[0] + c1 * (float)r1[0];
            a1 += c0 * (float)r0[1] + c1 * (float)r1[1];
            a2 += c0 * (float)r0[2] + c1 * (float)r1[2];
            a3 += c0 * (float)r0[3] + c1 * (float)r1[3];
        }
        if (j < cnt) {
            int   m0 = ml[j];
            float c0 = sc[j * 5 + h3];
            bf16x4 r0 = *(const bf16x4*)(v_base + (size_t)m0 * HID + colb);
            a0 += c0 * (float)r0[0];
            a1 += c0 * (float)r0[1];
            a2 += c0 * (float)r0[2];
            a3 += c0 * (float)r0[3];
        }
    }
    red[wave * 256 + colb + 0] = a0;
    red[wave * 256 + colb + 1] = a1;
    red[wave * 256 + colb + 2] = a2;
    red[wave * 256 + colb + 3] = a3;
    __syncthreads();
    float tot = red[t] + red[256 + t] + red[512 + t] + red[768 + t]
              + w0s[t >> 6] * vs[t];
    att[qrow * HID + t] = (bf16_t)tot;
}

// ---------------- final projection + residual (f32 out) ----------------------
__global__ __launch_bounds__(256)
void proj_out_kernel(const bf16_t* __restrict__ att, const bf16_t* __restrict__ wo,
                     const float* __restrict__ bo,
                     const float* __restrict__ e1, const float* __restrict__ e2,
                     float* __restrict__ out)
{
    int m0   = blockIdx.x * 64;
    int n0   = blockIdx.y * 64;      // in [0,256)
    int wave = threadIdx.x >> 6;
    int lane = threadIdx.x & 63;
    int r16  = lane & 15;
    int quad = lane >> 4;

    int arow = m0 + wave * 16 + r16;
    int rr   = arow < MTOT ? arow : MTOT - 1;
    const bf16_t* asrc = att + (size_t)rr * HID;

    f32x4 acc0 = {0,0,0,0}, acc1 = {0,0,0,0}, acc2 = {0,0,0,0}, acc3 = {0,0,0,0};
#pragma unroll
    for (int kk = 0; kk < HID; kk += 32) {
        bf16x8 a = *(const bf16x8*)(asrc + kk + quad * 8);
        const bf16_t* b0 = wo + (size_t)(n0 + r16) * HID + kk + quad * 8;
        bf16x8 f0 = *(const bf16x8*)(b0);
        bf16x8 f1 = *(const bf16x8*)(b0 + 16 * HID);
        bf16x8 f2 = *(const bf16x8*)(b0 + 32 * HID);
        bf16x8 f3 = *(const bf16x8*)(b0 + 48 * HID);
        acc0 = __builtin_amdgcn_mfma_f32_16x16x32_bf16(a, f0, acc0, 0, 0, 0);
        acc1 = __builtin_amdgcn_mfma_f32_16x16x32_bf16(a, f1, acc1, 0, 0, 0);
        acc2 = __builtin_amdgcn_mfma_f32_16x16x32_bf16(a, f2, acc2, 0, 0, 0);
        acc3 = __builtin_amdgcn_mfma_f32_16x16x32_bf16(a, f3, acc3, 0, 0, 0);
    }
    f32x4 accs[4] = {acc0, acc1, acc2, acc3};
    int rbase = m0 + wave * 16 + quad * 4;
#pragma unroll
    for (int nt = 0; nt < 4; ++nt) {
        int j = n0 + nt * 16 + r16;
        float bb = bo[j];
#pragma unroll
        for (int rg = 0; rg < 4; ++rg) {
            int r = rbase + rg;
            if (r < MTOT) {
                const float* emb = (r < NROW) ? (e1 + (size_t)r * HID)
                                              : (e2 + (size_t)(r - NROW) * HID);
                float v = accs[nt][rg] + bb + emb[j];
                out[(size_t)r * HID + j] = v;        // f32 out; concat row r -> r*256
            }
        }
    }
}

// ---------------- host launcher ----------------------------------------------
extern "C" void kernel_launch(void* const* d_in, const int* in_sizes, int n_in,
                              void* d_out, int out_size, void* d_ws, size_t ws_size,
                              hipStream_t stream)
{
    const float* e1 = (const float*)d_in[0];
    const float* e2 = (const float*)d_in[1];
    const float* am = (const float*)d_in[2];
    const float* wq = (const float*)d_in[3];
    const float* bq = (const float*)d_in[4];
    const float* wk = (const float*)d_in[5];
    const float* bk = (const float*)d_in[6];
    const float* wv = (const float*)d_in[7];
    const float* bv = (const float*)d_in[8];
    const float* wo = (const float*)d_in[9];
    const float* bo = (const float*)d_in[10];
    float* out = (float*)d_out;

    size_t off = 0;
    char* base = (char*)d_ws;
    auto alloc = [&](size_t bytes) -> void* {
        void* p = base + off;
        off += (bytes + 255) & ~(size_t)255;
        return p;
    };
    bf16_t* Q    = (bf16_t*)alloc((size_t)MTOT * HID * 2);
    bf16_t* Kf   = (bf16_t*)alloc((size_t)MTOT * HID * 2);
    bf16_t* V    = (bf16_t*)alloc((size_t)MTOT * HID * 2);
    bf16_t* Kbar = (bf16_t*)alloc((size_t)MTOT * HD * 2);
    bf16_t* att  = (bf16_t*)alloc((size_t)MTOT * HID * 2);
    bf16_t* cW   = (bf16_t*)alloc((size_t)4 * HID * HID * 2);   // Wq|Wk|Wv|Wo bf16
    int*    csr  = (int*)   alloc((size_t)NROW * CAP * 4);
    int*    csc  = (int*)   alloc((size_t)NROW * CAP * 4);
    // zeroed region: rcur | ccur | Vsum (contiguous)
    int*    rcur = (int*)   alloc(NROW * 4);
    int*    ccur = (int*)   alloc(NROW * 4);
    float*  Vsum = (float*) alloc(2 * HID * 4);

    size_t zero_bytes = (size_t)((char*)Vsum - (char*)rcur) + 2 * HID * 4;
    hipMemsetAsync(rcur, 0, zero_bytes, stream);

    // L1: weight canon + 16-wide align scan (independent halves)
    l1_canon_scan<<<CANON_BLOCKS + SCAN_BLOCKS, 256, 0, stream>>>(
        wq, wk, wv, wo, cW, am, rcur, csr);

    // L2: QKV projection + CSC scatter (both depend only on L1)
    l2_proj_csc<<<PROJ_BLOCKS + CSC_BLOCKS, 256, 0, stream>>>(
        e1, e2, cW, bq, bk, bv, Q, Kf, V, rcur, csr, ccur, csc);

    // L3: Kbar + Vsum
    kbar_vsum_kernel<<<3048, 256, 0, stream>>>(Kf, V, Kbar, Vsum);

    // L4: attention, both directions
    attn_kernel<<<dim3(NROW, 2), 256, 0, stream>>>(
        Q, Kbar, V, Vsum, rcur, ccur, csr, csc, att);

    // L5: final projection + residual (f32 output)
    proj_out_kernel<<<dim3(188, 4), 256, 0, stream>>>(
        att, cW + 3 * HID * HID, bo, e1, e2, out);
}

// Round 11
// 356.155 us; speedup vs baseline: 2.1733x; 1.0484x over previous
//
#include <hip/hip_runtime.h>
#include <hip/hip_bf16.h>
#include <stdint.h>

typedef __bf16 bf16_t;
typedef __bf16 bf16x8 __attribute__((ext_vector_type(8)));
typedef __bf16 bf16x4 __attribute__((ext_vector_type(4)));
typedef float f32x4 __attribute__((ext_vector_type(4)));

#define NROW 6000           // rows of each graph
#define HID 256
#define NHEAD 4
#define HD 64
#define ATT_SCALE 0.125f    // HEAD_DIM^-0.5 = 1/8
#define MTOT 12000          // both graphs concatenated
#define CAP 128             // ELL capacity; Binom(6000,0.01) mean 60 sd 7.7
#define NCH16 2250000       // 6000*6000/16 ; 375 chunks of 16 f32 per row exactly

#define SCAN_BLOCKS  ((NCH16 + 255) / 256)      // 8790
#define PROJ_BLOCKS  (188 * 12)                 // 2256
#define CSC_BLOCKS   ((NROW * CAP) / 256)       // 3000
#define WSTR 264                                // LDS weight row stride (pad vs banks)

// ============ K1: QKV projection (self-staged f32 weights)  ∥  align scan ====
// Proj blocks depend on nothing (weights converted in-block); scan blocks
// depend on nothing. Memory-bound scan overlaps MFMA-bound proj (m114).
__global__ __launch_bounds__(256)
void k1_proj_scan(const float* __restrict__ e1, const float* __restrict__ e2,
                  const float* __restrict__ wq, const float* __restrict__ wk,
                  const float* __restrict__ wv,
                  const float* __restrict__ bq, const float* __restrict__ bk,
                  const float* __restrict__ bv,
                  bf16_t* __restrict__ Q, bf16_t* __restrict__ Kf, bf16_t* __restrict__ V,
                  const float* __restrict__ am,
                  int* __restrict__ rcur,          // [NROW] pre-zeroed
                  int* __restrict__ csr)           // [NROW*CAP]
{
    __shared__ bf16_t lds_w[64 * WSTR];            // 33 KB, proj path only

    if (blockIdx.x < PROJ_BLOCKS) {
        // ---- projection: [12000,256] @ {Wq,Wk,Wv}^T + bias ----
        int bx   = blockIdx.x;
        int m0   = (bx % 188) * 64;
        int n0   = (bx / 188) * 64;      // output col in [0,768)
        int wave = threadIdx.x >> 6;
        int lane = threadIdx.x & 63;
        int r16  = lane & 15;
        int quad = lane >> 4;

        int sel = n0 >> 8;               // 0=Q, 1=K, 2=V
        int jb  = n0 & 255;
        const float* wsrc = (sel == 0) ? wq : (sel == 1) ? wk : wv;
        const float* bias = (sel == 0) ? bq : (sel == 1) ? bk : bv;

        // stage 64 weight rows f32 -> bf16 LDS (row stride WSTR)
        for (int i = threadIdx.x; i < 64 * 64; i += 256) {
            int row = i >> 6;            // 0..63
            int kq  = (i & 63) * 4;      // 0..252
            f32x4 w4 = *(const f32x4*)(wsrc + (size_t)(jb + row) * HID + kq);
            bf16x4 b4;
#pragma unroll
            for (int z = 0; z < 4; ++z) b4[z] = (bf16_t)w4[z];
            *(bf16x4*)(&lds_w[row * WSTR + kq]) = b4;
        }
        __syncthreads();

        int arow = m0 + wave * 16 + r16;
        int rr   = arow < MTOT ? arow : MTOT - 1;
        const float* asrc = (rr < NROW) ? (e1 + (size_t)rr * HID)
                                        : (e2 + (size_t)(rr - NROW) * HID);

        f32x4 acc0 = {0,0,0,0}, acc1 = {0,0,0,0}, acc2 = {0,0,0,0}, acc3 = {0,0,0,0};
#pragma unroll
        for (int kk = 0; kk < HID; kk += 32) {
            f32x4 af0 = *(const f32x4*)(asrc + kk + quad * 8);
            f32x4 af1 = *(const f32x4*)(asrc + kk + quad * 8 + 4);
            bf16x8 a;
#pragma unroll
            for (int i = 0; i < 4; ++i) { a[i] = (bf16_t)af0[i]; a[4 + i] = (bf16_t)af1[i]; }
            const bf16_t* b0 = lds_w + (size_t)r16 * WSTR + kk + quad * 8;
            bf16x8 f0 = *(const bf16x8*)(b0);
            bf16x8 f1 = *(const bf16x8*)(b0 + 16 * WSTR);
            bf16x8 f2 = *(const bf16x8*)(b0 + 32 * WSTR);
            bf16x8 f3 = *(const bf16x8*)(b0 + 48 * WSTR);
            acc0 = __builtin_amdgcn_mfma_f32_16x16x32_bf16(a, f0, acc0, 0, 0, 0);
            acc1 = __builtin_amdgcn_mfma_f32_16x16x32_bf16(a, f1, acc1, 0, 0, 0);
            acc2 = __builtin_amdgcn_mfma_f32_16x16x32_bf16(a, f2, acc2, 0, 0, 0);
            acc3 = __builtin_amdgcn_mfma_f32_16x16x32_bf16(a, f3, acc3, 0, 0, 0);
        }
        f32x4 accs[4] = {acc0, acc1, acc2, acc3};
        bf16_t* dst = (sel == 0) ? Q : (sel == 1) ? Kf : V;
        int rbase = m0 + wave * 16 + quad * 4;
#pragma unroll
        for (int nt = 0; nt < 4; ++nt) {
            int j = jb + nt * 16 + r16;
            float bb = bias[j];
#pragma unroll
            for (int rg = 0; rg < 4; ++rg) {
                int r = rbase + rg;
                if (r < MTOT)
                    dst[(size_t)r * HID + j] = (bf16_t)(accs[nt][rg] + bb);
            }
        }
        return;
    }

    // ---- scan: 16 f32 elements (64 B) per lane, wave-aggregated ELL ----
    int lane = threadIdx.x & 63;
    int ch   = (blockIdx.x - PROJ_BLOCKS) * 256 + threadIdx.x;
    bool oob = (ch >= NCH16);
    int che  = oob ? (NCH16 - 1) : ch;

    unsigned int nzmask = 0;
    if (!oob) {
        const uint4* p4 = (const uint4*)((const unsigned int*)am + (size_t)che * 16);
        uint4 u0 = p4[0], u1 = p4[1], u2 = p4[2], u3 = p4[3];
        unsigned int any = u0.x | u0.y | u0.z | u0.w | u1.x | u1.y | u1.z | u1.w
                         | u2.x | u2.y | u2.z | u2.w | u3.x | u3.y | u3.z | u3.w;
        if (any) {
            unsigned int w[16] = {u0.x, u0.y, u0.z, u0.w, u1.x, u1.y, u1.z, u1.w,
                                  u2.x, u2.y, u2.z, u2.w, u3.x, u3.y, u3.z, u3.w};
#pragma unroll
            for (int p = 0; p < 16; ++p)
                if (w[p]) nzmask |= 1u << p;
        }
    }
    int n  = che / 375;              // row of this chunk
    int m0 = (che - n * 375) * 16;   // first column of this chunk
    int c  = __popc(nzmask);

    // wave-wide exclusive prefix of c
    int p = c;
#pragma unroll
    for (int off = 1; off < 64; off <<= 1) {
        int t = __shfl_up(p, off);
        if (lane >= off) p += t;
    }
    int excl  = p - c;
    int total = __shfl(p, 63);

    int nFirst = __shfl(n, 0);
    int nLast  = __shfl(n, 63);
    unsigned long long mb = __ballot(n == nLast);
    int s0  = __ffsll(mb) - 1;       // first lane of the nLast segment
    int pS0 = __shfl(excl, s0);

    int baseB = 0;
    if (lane == s0) {
        int totalB = total - pS0;
        if (totalB > 0) baseB = atomicAdd(rcur + nLast, totalB);
    }
    baseB = __shfl(baseB, s0);
    int baseA = 0;
    if (s0 > 0) {                    // wave straddles two rows
        if (lane == 0 && pS0 > 0) baseA = atomicAdd(rcur + nFirst, pS0);
        baseA = __shfl(baseA, 0);
    }

    int myOff = (n == nLast) ? (baseB + excl - pS0) : (baseA + excl);
    if (c) {
        int* dst = csr + (size_t)n * CAP;
        int w = 0;
#pragma unroll
        for (int pb = 0; pb < 16; ++pb) {
            if (nzmask & (1u << pb)) {
                int idx = myOff + (w++);
                if (idx < CAP) dst[idx] = m0 + pb;
            }
        }
    }
}

// ============ K2: Kbar + Vsum  ∥  CSC-from-CSR scatter =======================
// Blocks [0,3000): Kbar. [3000,3048): Vsum. [3048,6048): CSC.
__global__ __launch_bounds__(256)
void k2_aux(const bf16_t* __restrict__ Kf, const bf16_t* __restrict__ V,
            bf16_t* __restrict__ Kbar, float* __restrict__ Vsum,
            const int* __restrict__ rcnt, const int* __restrict__ csr,
            int* __restrict__ ccur, int* __restrict__ csc)
{
    int b = blockIdx.x;
    if (b < 3000) {                       // Kbar: 12000*64 outputs
        int id = b * 256 + threadIdx.x;
        int m = id >> 6, d = id & 63;
        const bf16_t* kr = Kf + (size_t)m * HID + d;
        Kbar[id] = (bf16_t)(0.25f * ((float)kr[0] + (float)kr[64] +
                                     (float)kr[128] + (float)kr[192]));
    } else if (b < 3048) {                // Vsum: 2 graphs x 24 segments of 250
        int idx = b - 3000;
        int g = idx / 24;
        int seg = idx - g * 24;
        int j = threadIdx.x;
        const bf16_t* base = V + ((size_t)(g * NROW + seg * 250)) * HID + j;
        float s = 0.f;
        for (int m = 0; m < 250; ++m) s += (float)base[(size_t)m * HID];
        atomicAdd(Vsum + g * HID + j, s);
    } else {                              // CSC scatter
        int tid = (b - 3048) * 256 + threadIdx.x;   // n*CAP + j
        int n = tid >> 7, j = tid & (CAP - 1);
        if (n >= NROW) return;
        int cnt = rcnt[n]; if (cnt > CAP) cnt = CAP;
        if (j >= cnt) return;
        int m = csr[(size_t)n * CAP + j];
        int slot = atomicAdd(ccur + m, 1);
        if (slot < CAP) csc[(size_t)m * CAP + slot] = n;
    }
}

// ---------------- sparse-corrected attention (both directions) ---------------
// Exact softmax over 6000 kv entries: masked-out entries share weight e^-M/Z.
// Phase 1 on MFMA: scores = Kbar[rows]·q^T, A-fragments gathered directly from
// global (16B/lane, native A layout), B = q row (bf16, LDS), heads in C cols.
__global__ __launch_bounds__(256)
void attn_kernel(const bf16_t* __restrict__ Q, const bf16_t* __restrict__ Kbar,
                 const bf16_t* __restrict__ V, const float* __restrict__ Vsum,
                 const int* __restrict__ rcnt, const int* __restrict__ ccnt,
                 const int* __restrict__ csr, const int* __restrict__ csc,
                 bf16_t* __restrict__ att)
{
    __shared__ __align__(16) bf16_t qsb[HID];      // 0.5 KB, q row in bf16
    __shared__ int   ml[CAP];                      // 0.5 KB
    __shared__ float sc[CAP * 5];                  // 2.5 KB, [j][head] stride 5
    __shared__ float w0s[NHEAD];
    __shared__ float red[4 * HID];                 // 4 KB cross-wave reduction

    int dir = blockIdx.y;
    int n   = blockIdx.x;
    int t   = threadIdx.x;
    int wave = t >> 6, lane = t & 63;

    size_t qrow = (size_t)(dir ? NROW + n : n);
    const bf16_t* kb_base = Kbar + (dir ? 0 : (size_t)NROW * HD);
    const bf16_t* v_base  = V    + (dir ? 0 : (size_t)NROW * HID);
    const float*  vs      = Vsum + (dir ? 0 : HID);
    const int*    lst     = (dir ? csc : csr) + (size_t)n * CAP;
    int cnt = (dir ? ccnt : rcnt)[n];
    if (cnt > CAP) cnt = CAP;

    qsb[t] = Q[qrow * HID + t];
    for (int j = t; j < cnt; j += 256) ml[j] = lst[j];
    __syncthreads();

    int m16  = lane & 15;
    int quad = lane >> 4;

    // phase 1 (MFMA): per 16-j tile, scores[j][head] = SCALE * Kbar[mj]·q_head
    {
        bf16x8 b0, b1;
        if (m16 < NHEAD) {
            b0 = *(const bf16x8*)(qsb + m16 * HD + 0  + quad * 8);
            b1 = *(const bf16x8*)(qsb + m16 * HD + 32 + quad * 8);
        } else {
            b0 = (bf16x8)(bf16_t)0.f;
            b1 = (bf16x8)(bf16_t)0.f;
        }
        for (int jt = wave; jt * 16 < cnt; jt += 4) {
            int j  = jt * 16 + m16;
            int jj = j < cnt ? j : cnt - 1;           // clamp (cnt>0 here)
            int row = ml[jj];
            const bf16_t* ap = kb_base + (size_t)row * HD + quad * 8;
            bf16x8 a0 = *(const bf16x8*)(ap);
            bf16x8 a1 = *(const bf16x8*)(ap + 32);
            f32x4 acc = {0, 0, 0, 0};
            acc = __builtin_amdgcn_mfma_f32_16x16x32_bf16(a0, b0, acc, 0, 0, 0);
            acc = __builtin_amdgcn_mfma_f32_16x16x32_bf16(a1, b1, acc, 0, 0, 0);
            // C layout: col = lane&15 (head), row = quad*4 + rg (j within tile)
            if (m16 < NHEAD) {
#pragma unroll
                for (int rg = 0; rg < 4; ++rg) {
                    int jw = jt * 16 + quad * 4 + rg;
                    if (jw < cnt) sc[jw * 5 + m16] = acc[rg] * ATT_SCALE;
                }
            }
        }
    }
    __syncthreads();

    // phase 2: per-head exact softmax stats; wave `head` owns head `head`
    {
        int head = wave;
        float M = 0.0f;              // zero-score baseline always present
        for (int j = lane; j < cnt; j += 64) M = fmaxf(M, sc[j * 5 + head]);
        for (int off = 32; off; off >>= 1) M = fmaxf(M, __shfl_xor(M, off));
        float e0 = __expf(-M);
        float e[2]; int k = 0;
        float S = 0.f;
        for (int j = lane; j < cnt; j += 64, ++k) { e[k] = __expf(sc[j * 5 + head] - M); S += e[k]; }
        for (int off = 32; off; off >>= 1) S += __shfl_xor(S, off);
        float Z = S + (float)(NROW - cnt) * e0;
        float invZ = 1.0f / Z;
        k = 0;
        for (int j = lane; j < cnt; j += 64, ++k) sc[j * 5 + head] = (e[k] - e0) * invZ;
        if (lane == 0) w0s[head] = e0 * invZ;
    }
    __syncthreads();

    // phase 3: wave w handles j = w, w+4, ...; lane covers (h3, 4 dims).
    // 4-deep unroll keeps 4 V-row gathers in flight (L2-latency bound).
    int h3 = lane >> 4;
    int dq = lane & 15;
    int colb = h3 * HD + dq * 4;
    float a0 = 0.f, a1 = 0.f, a2 = 0.f, a3 = 0.f;
    {
        int j = wave;
        for (; j + 12 < cnt; j += 16) {
            int   m0 = ml[j];            int   m1 = ml[j + 4];
            int   m2 = ml[j + 8];        int   m3 = ml[j + 12];
            float c0 = sc[j * 5 + h3];   float c1 = sc[(j + 4) * 5 + h3];
            float c2 = sc[(j + 8) * 5 + h3]; float c3 = sc[(j + 12) * 5 + h3];
            bf16x4 r0 = *(const bf16x4*)(v_base + (size_t)m0 * HID + colb);
            bf16x4 r1 = *(const bf16x4*)(v_base + (size_t)m1 * HID + colb);
            bf16x4 r2 = *(const bf16x4*)(v_base + (size_t)m2 * HID + colb);
            bf16x4 r3 = *(const bf16x4*)(v_base + (size_t)m3 * HID + colb);
            a0 += c0 * (float)r0[0] + c1 * (float)r1[0] + c2 * (float)r2[0] + c3 * (float)r3[0];
            a1 += c0 * (float)r0[1] + c1 * (float)r1[1] + c2 * (float)r2[1] + c3 * (float)r3[1];
            a2 += c0 * (float)r0[2] + c1 * (float)r1[2] + c2 * (float)r2[2] + c3 * (float)r3[2];
            a3 += c0 * (float)r0[3] + c1 * (float)r1[3] + c2 * (float)r2[3] + c3 * (float)r3[3];
        }
        for (; j < cnt; j += 4) {
            int   m0 = ml[j];
            float c0 = sc[j * 5 + h3];
            bf16x4 r0 = *(const bf16x4*)(v_base + (size_t)m0 * HID + colb);
            a0 += c0 * (float)r0[0];
            a1 += c0 * (float)r0[1];
            a2 += c0 * (float)r0[2];
            a3 += c0 * (float)r0[3];
        }
    }
    red[wave * 256 + colb + 0] = a0;
    red[wave * 256 + colb + 1] = a1;
    red[wave * 256 + colb + 2] = a2;
    red[wave * 256 + colb + 3] = a3;
    __syncthreads();
    float tot = red[t] + red[256 + t] + red[512 + t] + red[768 + t]
              + w0s[t >> 6] * vs[t];
    att[qrow * HID + t] = (bf16_t)tot;
}

// ---------------- final projection + residual (self-staged Wo, f32 out) ------
__global__ __launch_bounds__(256)
void proj_out_kernel(const bf16_t* __restrict__ att, const float* __restrict__ wo,
                     const float* __restrict__ bo,
                     const float* __restrict__ e1, const float* __restrict__ e2,
                     float* __restrict__ out)
{
    __shared__ bf16_t lds_w[64 * WSTR];            // 33 KB

    int m0   = blockIdx.x * 64;
    int n0   = blockIdx.y * 64;      // in [0,256)
    int wave = threadIdx.x >> 6;
    int lane = threadIdx.x & 63;
    int r16  = lane & 15;
    int quad = lane >> 4;

    // stage Wo rows n0..n0+63 f32 -> bf16 LDS
    for (int i = threadIdx.x; i < 64 * 64; i += 256) {
        int row = i >> 6;
        int kq  = (i & 63) * 4;
        f32x4 w4 = *(const f32x4*)(wo + (size_t)(n0 + row) * HID + kq);
        bf16x4 b4;
#pragma unroll
        for (int z = 0; z < 4; ++z) b4[z] = (bf16_t)w4[z];
        *(bf16x4*)(&lds_w[row * WSTR + kq]) = b4;
    }
    __syncthreads();

    int arow = m0 + wave * 16 + r16;
    int rr   = arow < MTOT ? arow : MTOT - 1;
    const bf16_t* asrc = att + (size_t)rr * HID;

    f32x4 acc0 = {0,0,0,0}, acc1 = {0,0,0,0}, acc2 = {0,0,0,0}, acc3 = {0,0,0,0};
#pragma unroll
    for (int kk = 0; kk < HID; kk += 32) {
        bf16x8 a = *(const bf16x8*)(asrc + kk + quad * 8);
        const bf16_t* b0 = lds_w + (size_t)r16 * WSTR + kk + quad * 8;
        bf16x8 f0 = *(const bf16x8*)(b0);
        bf16x8 f1 = *(const bf16x8*)(b0 + 16 * WSTR);
        bf16x8 f2 = *(const bf16x8*)(b0 + 32 * WSTR);
        bf16x8 f3 = *(const bf16x8*)(b0 + 48 * WSTR);
        acc0 = __builtin_amdgcn_mfma_f32_16x16x32_bf16(a, f0, acc0, 0, 0, 0);
        acc1 = __builtin_amdgcn_mfma_f32_16x16x32_bf16(a, f1, acc1, 0, 0, 0);
        acc2 = __builtin_amdgcn_mfma_f32_16x16x32_bf16(a, f2, acc2, 0, 0, 0);
        acc3 = __builtin_amdgcn_mfma_f32_16x16x32_bf16(a, f3, acc3, 0, 0, 0);
    }
    f32x4 accs[4] = {acc0, acc1, acc2, acc3};
    int rbase = m0 + wave * 16 + quad * 4;
#pragma unroll
    for (int nt = 0; nt < 4; ++nt) {
        int j = n0 + nt * 16 + r16;
        float bb = bo[j];
#pragma unroll
        for (int rg = 0; rg < 4; ++rg) {
            int r = rbase + rg;
            if (r < MTOT) {
                const float* emb = (r < NROW) ? (e1 + (size_t)r * HID)
                                              : (e2 + (size_t)(r - NROW) * HID);
                float v = accs[nt][rg] + bb + emb[j];
                out[(size_t)r * HID + j] = v;        // f32 out; concat row r -> r*256
            }
        }
    }
}

// ---------------- host launcher ----------------------------------------------
extern "C" void kernel_launch(void* const* d_in, const int* in_sizes, int n_in,
                              void* d_out, int out_size, void* d_ws, size_t ws_size,
                              hipStream_t stream)
{
    const float* e1 = (const float*)d_in[0];
    const float* e2 = (const float*)d_in[1];
    const float* am = (const float*)d_in[2];
    const float* wq = (const float*)d_in[3];
    const float* bq = (const float*)d_in[4];
    const float* wk = (const float*)d_in[5];
    const float* bk = (const float*)d_in[6];
    const float* wv = (const float*)d_in[7];
    const float* bv = (const float*)d_in[8];
    const float* wo = (const float*)d_in[9];
    const float* bo = (const float*)d_in[10];
    float* out = (float*)d_out;

    size_t off = 0;
    char* base = (char*)d_ws;
    auto alloc = [&](size_t bytes) -> void* {
        void* p = base + off;
        off += (bytes + 255) & ~(size_t)255;
        return p;
    };
    bf16_t* Q    = (bf16_t*)alloc((size_t)MTOT * HID * 2);
    bf16_t* Kf   = (bf16_t*)alloc((size_t)MTOT * HID * 2);
    bf16_t* V    = (bf16_t*)alloc((size_t)MTOT * HID * 2);
    bf16_t* Kbar = (bf16_t*)alloc((size_t)MTOT * HD * 2);
    bf16_t* att  = (bf16_t*)alloc((size_t)MTOT * HID * 2);
    int*    csr  = (int*)   alloc((size_t)NROW * CAP * 4);
    int*    csc  = (int*)   alloc((size_t)NROW * CAP * 4);
    // zeroed region: rcur | ccur | Vsum (contiguous)
    int*    rcur = (int*)   alloc(NROW * 4);
    int*    ccur = (int*)   alloc(NROW * 4);
    float*  Vsum = (float*) alloc(2 * HID * 4);

    size_t zero_bytes = (size_t)((char*)Vsum - (char*)rcur) + 2 * HID * 4;
    hipMemsetAsync(rcur, 0, zero_bytes, stream);

    // K1: QKV projection (self-staged weights) ∥ 16-wide align scan
    k1_proj_scan<<<PROJ_BLOCKS + SCAN_BLOCKS, 256, 0, stream>>>(
        e1, e2, wq, wk, wv, bq, bk, bv, Q, Kf, V, am, rcur, csr);

    // K2: Kbar + Vsum ∥ CSC scatter (all depend only on K1)
    k2_aux<<<6048, 256, 0, stream>>>(Kf, V, Kbar, Vsum, rcur, csr, ccur, csc);

    // K3: attention, both directions
    attn_kernel<<<dim3(NROW, 2), 256, 0, stream>>>(
        Q, Kbar, V, Vsum, rcur, ccur, csr, csc, att);

    // K4: final projection + residual (self-staged Wo, f32 output)
    proj_out_kernel<<<dim3(188, 4), 256, 0, stream>>>(att, wo, bo, e1, e2, out);
}